// Round 5
// baseline (327.556 us; speedup 1.0000x reference)
//
#include <hip/hip_runtime.h>
#include <stdint.h>

// Toeplitz matvec = circular conv via batched 4096-pt radix-16 FFT (3 stages).
// Per block: TWO real columns packed z = x[:,e0] + i*x[:,e0+1] (conv is
// real-linear -> out_e0 = Re, out_e1 = Im).
// v5: reads x fp32 directly (no transpose/bf16 prepass); LDS exactly 32 KB
// via XOR bank swizzle (5 blocks/CU); stage1 fused w/ load (zero-pad pruned),
// stage5 fused w/ store (output pruned); one combined table+V prepass kernel.
// ws: tw4096 float2[4096], tw256 float2[256], V2 float2[4096].

#define B_ 8
#define N_ 2048
#define NF 4096
#define E_ 1024

// XOR swizzle: permutes low4 (bank-pair for b64) by higher bits. All phase
// patterns (t+256r / g*256+16r+j / 16t+r) land exactly 4 lanes per bank-pair
// per wave b64 op = conflict floor.
__device__ __forceinline__ int P(int n) { return n ^ ((n >> 4) & 15) ^ ((n >> 8) & 15); }
#define PERM(r) ((((r) & 3) << 2) | ((r) >> 2))   // DFT16 reg<->index transpose

__device__ __forceinline__ void cmul(float& ar, float& ai, float br, float bi) {
    float t = ar * br - ai * bi; ai = ar * bi + ai * br; ar = t;
}
__device__ __forceinline__ void cmulc(float& ar, float& ai, float br, float bi) {
    float t = ar * br + ai * bi; ai = ai * br - ar * bi; ar = t;   // a *= conj(b)
}

__device__ __forceinline__ void dft4(float& x0r, float& x0i, float& x1r, float& x1i,
                                     float& x2r, float& x2i, float& x3r, float& x3i,
                                     float sg) {
    float t0r = x0r + x2r, t0i = x0i + x2i;
    float t1r = x0r - x2r, t1i = x0i - x2i;
    float t2r = x1r + x3r, t2i = x1i + x3i;
    float t3r = x1r - x3r, t3i = x1i - x3i;
    x0r = t0r + t2r; x0i = t0i + t2i;
    x2r = t0r - t2r; x2i = t0i - t2i;
    x1r = t1r - sg * t3i; x1i = t1i + sg * t3r;
    x3r = t1r + sg * t3i; x3i = t1i - sg * t3r;
}

template<int SG>
__device__ __forceinline__ void dft16_layer1(float* xr, float* xi) {
    const float sg = (float)SG;
#pragma unroll
    for (int n0 = 0; n0 < 4; ++n0)
        dft4(xr[n0], xi[n0], xr[n0 + 4], xi[n0 + 4],
             xr[n0 + 8], xi[n0 + 8], xr[n0 + 12], xi[n0 + 12], sg);
}
// upper 8 inputs (slots 8..15) known zero
template<int SG>
__device__ __forceinline__ void dft16_layer1_pad(float* xr, float* xi) {
    const float sg = (float)SG;
#pragma unroll
    for (int n0 = 0; n0 < 4; ++n0) {
        float ar = xr[n0], ai = xi[n0], br = xr[n0 + 4], bi = xi[n0 + 4];
        xr[n0]      = ar + br;       xi[n0]      = ai + bi;
        xr[n0 + 4]  = ar - sg * bi;  xi[n0 + 4]  = ai + sg * br;
        xr[n0 + 8]  = ar - br;       xi[n0 + 8]  = ai - bi;
        xr[n0 + 12] = ar + sg * bi;  xi[n0 + 12] = ai - sg * br;
    }
}
template<int SG>
__device__ __forceinline__ void dft16_twiddle(float* xr, float* xi) {
    const float sg = (float)SG;
    const float C1 = 0.923879532511286756f;
    const float S1 = 0.382683432365089772f;
    const float H  = 0.707106781186547524f;
    cmul(xr[5],  xi[5],  C1,  sg * S1);
    cmul(xr[9],  xi[9],  H,   sg * H);
    cmul(xr[13], xi[13], S1,  sg * C1);
    cmul(xr[6],  xi[6],  H,   sg * H);
    cmul(xr[10], xi[10], 0.f, sg);
    cmul(xr[14], xi[14], -H,  sg * H);
    cmul(xr[7],  xi[7],  S1,  sg * C1);
    cmul(xr[11], xi[11], -H,  sg * H);
    cmul(xr[15], xi[15], -C1, -sg * S1);
}
template<int SG>
__device__ __forceinline__ void dft16_layer2(float* xr, float* xi) {
    const float sg = (float)SG;
#pragma unroll
    for (int k1 = 0; k1 < 4; ++k1)
        dft4(xr[4 * k1], xi[4 * k1], xr[4 * k1 + 1], xi[4 * k1 + 1],
             xr[4 * k1 + 2], xi[4 * k1 + 2], xr[4 * k1 + 3], xi[4 * k1 + 3], sg);
}
template<int SG>
__device__ __forceinline__ void dft16(float* xr, float* xi) {
    dft16_layer1<SG>(xr, xi);
    dft16_twiddle<SG>(xr, xi);
    dft16_layer2<SG>(xr, xi);
}

// forward radix-16 stage with inline sincos twiddles (build_V only, 1 block)
template<int L>
__device__ __forceinline__ void fwd_stage_sincos(float2* buf, int t) {
    constexpr int Lq = L / 16;
    int g = t / Lq;
    int j = t - g * Lq;
    int base = g * L + j;
    const float TPI = -6.28318530717958647692f;
    float xr[16], xi[16];
#pragma unroll
    for (int r = 0; r < 16; ++r) {
        float2 v = buf[P(base + r * Lq)];
        xr[r] = v.x; xi[r] = v.y;
    }
    dft16<-1>(xr, xi);
    { float2 v; v.x = xr[0]; v.y = xi[0]; buf[P(base)] = v; }
#pragma unroll
    for (int r = 1; r < 16; ++r) {
        float s, c;
        __sincosf(TPI * (float)(j * r) * (1.f / (float)L), &s, &c);
        float yr = xr[PERM(r)], yi = xi[PERM(r)];
        cmul(yr, yi, c, s);
        float2 v; v.x = yr; v.y = yi;
        buf[P(base + r * Lq)] = v;
    }
}

// ---------------- prepass: twiddle tables + V, one kernel --------------------
// blk 0..15: tw4096[r*256+j] = cis(-2pi r j/4096), r=blk
// blk 16:    tw256[r*16+j]   = cis(-2pi r j/256)
// blk 17:    V2 = DIF(a)/4096 in raw digit-reversed slots
__global__ __launch_bounds__(256) void build_tables(const float* __restrict__ pos,
                                                    const float* __restrict__ zero,
                                                    const float* __restrict__ neg,
                                                    float2* __restrict__ tw4096,
                                                    float2* __restrict__ tw256,
                                                    float2* __restrict__ V2) {
    __shared__ float2 buf[NF];
    const float TPI = -6.28318530717958647692f;
    int blk = blockIdx.x, t = threadIdx.x;
    if (blk < 16) {
        float s, c;
        __sincosf(TPI * (float)(blk * t) * (1.f / 4096.f), &s, &c);
        float2 v; v.x = c; v.y = s;
        tw4096[blk * 256 + t] = v;
    } else if (blk == 16) {
        int r = t >> 4, j = t & 15;
        float s, c;
        __sincosf(TPI * (float)(r * j) * (1.f / 256.f), &s, &c);
        float2 v; v.x = c; v.y = s;
        tw256[t] = v;
    } else {
#pragma unroll
        for (int it = 0; it < 16; ++it) {
            int n = t + 256 * it;
            float v;
            if (n == 0) v = zero[0];
            else if (n < N_) v = pos[n - 1];
            else if (n == N_) v = zero[0];
            else v = neg[n - (N_ + 1)];
            float2 cc; cc.x = v; cc.y = 0.f;
            buf[P(n)] = cc;
        }
        __syncthreads();
        fwd_stage_sincos<4096>(buf, t); __syncthreads();
        fwd_stage_sincos<256>(buf, t);  __syncthreads();
        fwd_stage_sincos<16>(buf, t);   __syncthreads();
        const float s = 1.f / (float)NF;
#pragma unroll
        for (int it = 0; it < 16; ++it) {
            int n = t + 256 * it;
            float2 c = buf[P(n)];
            c.x *= s; c.y *= s;
            V2[n] = c;
        }
    }
}

// ---------------- main: FFT-conv, one column pair per block ------------------
__global__ __launch_bounds__(256, 5) void fft_conv(const float* __restrict__ x,
                                                   const float2* __restrict__ tw4096,
                                                   const float2* __restrict__ tw256,
                                                   const float2* __restrict__ V2,
                                                   float* __restrict__ out) {
    __shared__ float2 buf[NF];              // exactly 32 KB -> 5 blocks/CU
    int t = threadIdx.x;
    int bid = blockIdx.x;
    int xcd = bid & 7;                      // e-adjacent blocks share an XCD:
    int q = bid >> 3;                       // merges both read & write lines in L2
    int b = q >> 6;
    int e0 = (xcd * 64 + (q & 63)) * 2;

    const float* xb = x + ((size_t)b * N_) * E_ + e0;

    float xr[16], xi[16];

    // ---- Phase A: fwd L=4096 straight from global (fp32); slots 8..15 zero
#pragma unroll
    for (int r = 0; r < 8; ++r) {
        float2 v = *(const float2*)(xb + (size_t)(t + 256 * r) * E_);
        xr[r] = v.x; xi[r] = v.y;
    }
#pragma unroll
    for (int r = 8; r < 16; ++r) { xr[r] = 0.f; xi[r] = 0.f; }
    dft16_layer1_pad<-1>(xr, xi);
    dft16_twiddle<-1>(xr, xi);
    dft16_layer2<-1>(xr, xi);
    { float2 v; v.x = xr[0]; v.y = xi[0]; buf[P(t)] = v; }
#pragma unroll
    for (int r = 1; r < 16; ++r) {
        float2 w = tw4096[r * 256 + t];
        float yr = xr[PERM(r)], yi = xi[PERM(r)];
        cmul(yr, yi, w.x, w.y);
        float2 v; v.x = yr; v.y = yi;
        buf[P(t + 256 * r)] = v;
    }
    __syncthreads();

    // ---- Phase B: fwd L=256
    int g = t >> 4, j = t & 15;
    int base = g * 256 + j;
#pragma unroll
    for (int r = 0; r < 16; ++r) {
        float2 v = buf[P(base + 16 * r)];
        xr[r] = v.x; xi[r] = v.y;
    }
    dft16<-1>(xr, xi);
    { float2 v; v.x = xr[0]; v.y = xi[0]; buf[P(base)] = v; }
#pragma unroll
    for (int r = 1; r < 16; ++r) {
        float2 w = tw256[r * 16 + j];
        float yr = xr[PERM(r)], yi = xi[PERM(r)];
        cmul(yr, yi, w.x, w.y);
        float2 v; v.x = yr; v.y = yi;
        buf[P(base + 16 * r)] = v;
    }
    __syncthreads();

    // ---- Phase C: fwd L=16 (no twiddle) + pointwise*V + inv L=16, in regs
    {
        int mb = 16 * t;
#pragma unroll
        for (int r = 0; r < 16; ++r) {
            float2 v = buf[P(mb + r)];
            xr[r] = v.x; xi[r] = v.y;
        }
        dft16<-1>(xr, xi);
        float yr2[16], yi2[16];
        const float4* Vv = (const float4*)(V2 + mb);
#pragma unroll
        for (int h = 0; h < 8; ++h) {
            float4 vv = Vv[h];
            int r = 2 * h;
            float ar = xr[PERM(r)], ai = xi[PERM(r)];
            yr2[r] = ar * vv.x - ai * vv.y;
            yi2[r] = ar * vv.y + ai * vv.x;
            r = 2 * h + 1;
            ar = xr[PERM(r)]; ai = xi[PERM(r)];
            yr2[r] = ar * vv.z - ai * vv.w;
            yi2[r] = ar * vv.w + ai * vv.z;
        }
        dft16<1>(yr2, yi2);
#pragma unroll
        for (int r = 0; r < 16; ++r) {
            float2 v; v.x = yr2[PERM(r)]; v.y = yi2[PERM(r)];
            buf[P(mb + r)] = v;
        }
    }
    __syncthreads();

    // ---- Phase D: inv L=256
#pragma unroll
    for (int r = 0; r < 16; ++r) {
        float2 v = buf[P(base + 16 * r)];
        xr[r] = v.x; xi[r] = v.y;
    }
#pragma unroll
    for (int r = 1; r < 16; ++r) {
        float2 w = tw256[r * 16 + j];
        cmulc(xr[r], xi[r], w.x, w.y);
    }
    dft16<1>(xr, xi);
#pragma unroll
    for (int r = 0; r < 16; ++r) {
        float2 v; v.x = xr[PERM(r)]; v.y = xi[PERM(r)];
        buf[P(base + 16 * r)] = v;
    }
    __syncthreads();

    // ---- Phase E: inv L=4096, pruned output (k<2048) straight to global
#pragma unroll
    for (int r = 0; r < 16; ++r) {
        float2 v = buf[P(t + 256 * r)];
        xr[r] = v.x; xi[r] = v.y;
    }
#pragma unroll
    for (int r = 1; r < 16; ++r) {
        float2 w = tw4096[r * 256 + t];
        cmulc(xr[r], xi[r], w.x, w.y);
    }
    dft16_layer1<1>(xr, xi);
    dft16_twiddle<1>(xr, xi);
    float* ob = out + ((size_t)b * N_) * E_ + e0;
#pragma unroll
    for (int k1 = 0; k1 < 4; ++k1) {
        float a0r = xr[4 * k1],     a0i = xi[4 * k1];
        float a1r = xr[4 * k1 + 1], a1i = xi[4 * k1 + 1];
        float a2r = xr[4 * k1 + 2], a2i = xi[4 * k1 + 2];
        float a3r = xr[4 * k1 + 3], a3i = xi[4 * k1 + 3];
        float t0r = a0r + a2r, t0i = a0i + a2i;
        float t1r = a0r - a2r, t1i = a0i - a2i;
        float t2r = a1r + a3r, t2i = a1i + a3i;
        float t3r = a1r - a3r, t3i = a1i - a3i;
        float2 v0; v0.x = t0r + t2r; v0.y = t0i + t2i;           // k = t+256*k1
        float2 v1; v1.x = t1r - t3i; v1.y = t1i + t3r;           // k = t+256*(k1+4)
        *(float2*)(ob + (size_t)(t + 256 * k1) * E_)       = v0;
        *(float2*)(ob + (size_t)(t + 256 * (k1 + 4)) * E_) = v1;
    }
}

// ---------------- fallback (ws too small): direct fp32 dot -------------------
__global__ __launch_bounds__(256) void naive_toep(const float* __restrict__ x,
                                                  const float* __restrict__ pos,
                                                  const float* __restrict__ zero,
                                                  const float* __restrict__ neg,
                                                  float* __restrict__ out) {
    int bid = blockIdx.x;
    int e   = (bid & 3) * 256 + threadIdx.x;
    int k   = (bid >> 2) & (N_ - 1);
    int b   = bid >> 13;
    float zv = zero[0];
    float acc = 0.f;
    const float* xb = x + (size_t)b * N_ * E_ + e;
    for (int jj = 0; jj < N_; ++jj) {
        float c = (jj < k) ? pos[k - jj - 1] : (jj == k) ? zv : neg[N_ - 1 - jj + k];
        acc += c * xb[(size_t)jj * E_];
    }
    out[((size_t)(b * N_ + k)) * E_ + e] = acc;
}

extern "C" void kernel_launch(void* const* d_in, const int* in_sizes, int n_in,
                              void* d_out, int out_size, void* d_ws, size_t ws_size,
                              hipStream_t stream) {
    const float* x    = (const float*)d_in[0];
    const float* pos  = (const float*)d_in[1];
    const float* zero = (const float*)d_in[2];
    const float* neg  = (const float*)d_in[3];
    float* out = (float*)d_out;

    const size_t need = (2 * (size_t)NF + 256) * sizeof(float2);
    if (ws_size >= need) {
        float2* tw4096 = (float2*)d_ws;
        float2* tw256  = tw4096 + NF;
        float2* V2     = tw256 + 256;
        build_tables<<<18, 256, 0, stream>>>(pos, zero, neg, tw4096, tw256, V2);
        fft_conv<<<4096, 256, 0, stream>>>(x, tw4096, tw256, V2, out);
    } else {
        naive_toep<<<65536, 256, 0, stream>>>(x, pos, zero, neg, out);
    }
}

// Round 6
// 278.631 us; speedup vs baseline: 1.1756x; 1.1756x over previous
//
#include <hip/hip_runtime.h>
#include <stdint.h>

// Toeplitz matvec = circular conv via batched 4096-pt radix-16 FFT (3 stages).
// Per block: TWO real columns packed z = x[:,e0] + i*x[:,e0+1] (conv is
// real-linear -> out_e0 = Re, out_e1 = Im).
// v6: bf16 transposed xT read path restored (R5 showed direct fp32 reads are
// an 8B/64B-line gather: FETCH 10x, store-merge broken). Exact-32KB LDS with
// a full XOR bank swizzle that hits the 2-way floor on ALL phase patterns;
// 5 blocks/CU. One fused prep kernel (transpose + twiddle tables + V).
// ws: xT bf16[8][1024][2048] (32MiB) + tw4096 f2[4096] + tw256 f2[256] + V2 f2[4096].

#define B_ 8
#define N_ 2048
#define NF 4096
#define E_ 1024

// Bank swizzle (b64 accesses: bank-pair = idx mod 32). Patterns per wave:
//  A/E: n=t+256r   -> varying n0-5        B/D: n=256g+16r+j -> varying n0-3,n8-9
//  C:   n=16t+r    -> varying n4-9
// low4 ^= n4-7 ^ n8-11, bit4 ^= n9  => every pattern lands 2 lanes/bank-pair
// (the wave64 floor, free per m136). Bijective on [0,4096).
__device__ __forceinline__ int P(int n) {
    return n ^ ((n >> 4) & 15) ^ ((n >> 8) & 15) ^ (((n >> 9) & 1) << 4);
}
#define PERM(r) ((((r) & 3) << 2) | ((r) >> 2))   // DFT16 reg<->index transpose

__device__ __forceinline__ unsigned short f32_to_bf16_rne(float f) {
    union { float f; unsigned int u; } cv; cv.f = f;
    unsigned int u = cv.u;
    u += 0x7fffu + ((u >> 16) & 1u);
    return (unsigned short)(u >> 16);
}
__device__ __forceinline__ float bf16_to_f32(unsigned short u) {
    union { unsigned int u; float f; } cv; cv.u = ((unsigned int)u) << 16; return cv.f;
}
__device__ __forceinline__ void cmul(float& ar, float& ai, float br, float bi) {
    float t = ar * br - ai * bi; ai = ar * bi + ai * br; ar = t;
}
__device__ __forceinline__ void cmulc(float& ar, float& ai, float br, float bi) {
    float t = ar * br + ai * bi; ai = ai * br - ar * bi; ar = t;   // a *= conj(b)
}

__device__ __forceinline__ void dft4(float& x0r, float& x0i, float& x1r, float& x1i,
                                     float& x2r, float& x2i, float& x3r, float& x3i,
                                     float sg) {
    float t0r = x0r + x2r, t0i = x0i + x2i;
    float t1r = x0r - x2r, t1i = x0i - x2i;
    float t2r = x1r + x3r, t2i = x1i + x3i;
    float t3r = x1r - x3r, t3i = x1i - x3i;
    x0r = t0r + t2r; x0i = t0i + t2i;
    x2r = t0r - t2r; x2i = t0i - t2i;
    x1r = t1r - sg * t3i; x1i = t1i + sg * t3r;
    x3r = t1r + sg * t3i; x3i = t1i - sg * t3r;
}

template<int SG>
__device__ __forceinline__ void dft16_layer1(float* xr, float* xi) {
    const float sg = (float)SG;
#pragma unroll
    for (int n0 = 0; n0 < 4; ++n0)
        dft4(xr[n0], xi[n0], xr[n0 + 4], xi[n0 + 4],
             xr[n0 + 8], xi[n0 + 8], xr[n0 + 12], xi[n0 + 12], sg);
}
// upper 8 inputs (slots 8..15) known zero
template<int SG>
__device__ __forceinline__ void dft16_layer1_pad(float* xr, float* xi) {
    const float sg = (float)SG;
#pragma unroll
    for (int n0 = 0; n0 < 4; ++n0) {
        float ar = xr[n0], ai = xi[n0], br = xr[n0 + 4], bi = xi[n0 + 4];
        xr[n0]      = ar + br;       xi[n0]      = ai + bi;
        xr[n0 + 4]  = ar - sg * bi;  xi[n0 + 4]  = ai + sg * br;
        xr[n0 + 8]  = ar - br;       xi[n0 + 8]  = ai - bi;
        xr[n0 + 12] = ar + sg * bi;  xi[n0 + 12] = ai - sg * br;
    }
}
template<int SG>
__device__ __forceinline__ void dft16_twiddle(float* xr, float* xi) {
    const float sg = (float)SG;
    const float C1 = 0.923879532511286756f;
    const float S1 = 0.382683432365089772f;
    const float H  = 0.707106781186547524f;
    cmul(xr[5],  xi[5],  C1,  sg * S1);
    cmul(xr[9],  xi[9],  H,   sg * H);
    cmul(xr[13], xi[13], S1,  sg * C1);
    cmul(xr[6],  xi[6],  H,   sg * H);
    cmul(xr[10], xi[10], 0.f, sg);
    cmul(xr[14], xi[14], -H,  sg * H);
    cmul(xr[7],  xi[7],  S1,  sg * C1);
    cmul(xr[11], xi[11], -H,  sg * H);
    cmul(xr[15], xi[15], -C1, -sg * S1);
}
template<int SG>
__device__ __forceinline__ void dft16_layer2(float* xr, float* xi) {
    const float sg = (float)SG;
#pragma unroll
    for (int k1 = 0; k1 < 4; ++k1)
        dft4(xr[4 * k1], xi[4 * k1], xr[4 * k1 + 1], xi[4 * k1 + 1],
             xr[4 * k1 + 2], xi[4 * k1 + 2], xr[4 * k1 + 3], xi[4 * k1 + 3], sg);
}
template<int SG>
__device__ __forceinline__ void dft16(float* xr, float* xi) {
    dft16_layer1<SG>(xr, xi);
    dft16_twiddle<SG>(xr, xi);
    dft16_layer2<SG>(xr, xi);
}

// forward radix-16 stage with inline sincos twiddles (V build only, 1 block)
template<int L>
__device__ __forceinline__ void fwd_stage_sincos(float2* buf, int t) {
    constexpr int Lq = L / 16;
    int g = t / Lq;
    int j = t - g * Lq;
    int base = g * L + j;
    const float TPI = -6.28318530717958647692f;
    float xr[16], xi[16];
#pragma unroll
    for (int r = 0; r < 16; ++r) {
        float2 v = buf[P(base + r * Lq)];
        xr[r] = v.x; xi[r] = v.y;
    }
    dft16<-1>(xr, xi);
    { float2 v; v.x = xr[0]; v.y = xi[0]; buf[P(base)] = v; }
#pragma unroll
    for (int r = 1; r < 16; ++r) {
        float s, c;
        __sincosf(TPI * (float)(j * r) * (1.f / (float)L), &s, &c);
        float yr = xr[PERM(r)], yi = xi[PERM(r)];
        cmul(yr, yi, c, s);
        float2 v; v.x = yr; v.y = yi;
        buf[P(base + r * Lq)] = v;
    }
}

// ---------------- prep: tables + V + transpose, single launch ----------------
// blk 0..15 : tw4096[r*256+j] = cis(-2pi r j/4096), r=blk
// blk 16    : tw256[r*16+j]   = cis(-2pi r j/256)
// blk 17    : V2 = DIF(a)/4096, raw digit-reversed slots
// blk 18+   : x [b][j][e] fp32 -> xT [b][e][j] bf16, 64x64 tiles
__global__ __launch_bounds__(256) void prep(const float* __restrict__ x,
                                            const float* __restrict__ pos,
                                            const float* __restrict__ zero,
                                            const float* __restrict__ neg,
                                            unsigned short* __restrict__ xT,
                                            float2* __restrict__ tw4096,
                                            float2* __restrict__ tw256,
                                            float2* __restrict__ V2) {
    __shared__ __align__(16) char smraw[32768];
    const float TPI = -6.28318530717958647692f;
    int blk = blockIdx.x, t = threadIdx.x;
    if (blk < 16) {
        float s, c;
        __sincosf(TPI * (float)(blk * t) * (1.f / 4096.f), &s, &c);
        float2 v; v.x = c; v.y = s;
        tw4096[blk * 256 + t] = v;
    } else if (blk == 16) {
        int r = t >> 4, j = t & 15;
        float s, c;
        __sincosf(TPI * (float)(r * j) * (1.f / 256.f), &s, &c);
        float2 v; v.x = c; v.y = s;
        tw256[t] = v;
    } else if (blk == 17) {
        float2* buf = (float2*)smraw;
#pragma unroll
        for (int it = 0; it < 16; ++it) {
            int n = t + 256 * it;
            float v;
            if (n == 0) v = zero[0];
            else if (n < N_) v = pos[n - 1];
            else if (n == N_) v = zero[0];
            else v = neg[n - (N_ + 1)];
            float2 cc; cc.x = v; cc.y = 0.f;
            buf[P(n)] = cc;
        }
        __syncthreads();
        fwd_stage_sincos<4096>(buf, t); __syncthreads();
        fwd_stage_sincos<256>(buf, t);  __syncthreads();
        fwd_stage_sincos<16>(buf, t);   __syncthreads();
        const float s = 1.f / (float)NF;
#pragma unroll
        for (int it = 0; it < 16; ++it) {
            int n = t + 256 * it;
            float2 c = buf[P(n)];
            c.x *= s; c.y *= s;
            V2[n] = c;
        }
    } else {
        float (*tile)[66] = (float (*)[66])smraw;    // 64*66*4 = 16.9 KB
        int tid = blk - 18;
        int e0 = (tid & 15) * 64;
        int j0 = ((tid >> 4) & 31) * 64;
        int b  = tid >> 9;
        int e4 = t & 15, jr = t >> 4;
#pragma unroll
        for (int it = 0; it < 4; ++it) {
            int j = jr + it * 16;
            const float4 v = *(const float4*)(x + ((size_t)(b * N_ + j0 + j) * E_) + e0 + e4 * 4);
            tile[e4 * 4 + 0][j] = v.x;
            tile[e4 * 4 + 1][j] = v.y;
            tile[e4 * 4 + 2][j] = v.z;
            tile[e4 * 4 + 3][j] = v.w;
        }
        __syncthreads();
        int j2 = (t & 31) * 2, er = t >> 5;
#pragma unroll
        for (int it = 0; it < 8; ++it) {
            int e = er + it * 8;
            float2 v = *(const float2*)&tile[e][j2];
            union { unsigned short s[2]; unsigned int u; } pk;
            pk.s[0] = f32_to_bf16_rne(v.x);
            pk.s[1] = f32_to_bf16_rne(v.y);
            *(unsigned int*)(xT + ((size_t)(b * E_ + e0 + e)) * N_ + j0 + j2) = pk.u;
        }
    }
}

// ---------------- main: FFT-conv, one column pair per block ------------------
__global__ __launch_bounds__(256, 5) void fft_conv(const unsigned short* __restrict__ xT,
                                                   const float2* __restrict__ tw4096,
                                                   const float2* __restrict__ tw256,
                                                   const float2* __restrict__ V2,
                                                   float* __restrict__ out) {
    __shared__ float2 buf[NF];              // exactly 32 KB -> 5 blocks/CU
    int t = threadIdx.x;
    int bid = blockIdx.x;
    int xcd = bid & 7;                      // e-adjacent blocks share an XCD
    int q = bid >> 3;
    int b = q >> 6;
    int e0 = (xcd * 64 + (q & 63)) * 2;

    const unsigned short* r0 = xT + ((size_t)(b * E_ + e0)) * N_;
    const unsigned short* r1 = r0 + N_;

    float xr[16], xi[16];

    // ---- Phase A: fwd L=4096 straight from xT (bf16 rows); slots 8..15 zero
#pragma unroll
    for (int r = 0; r < 8; ++r) {
        int n = t + 256 * r;
        xr[r] = bf16_to_f32(r0[n]);
        xi[r] = bf16_to_f32(r1[n]);
    }
#pragma unroll
    for (int r = 8; r < 16; ++r) { xr[r] = 0.f; xi[r] = 0.f; }
    dft16_layer1_pad<-1>(xr, xi);
    dft16_twiddle<-1>(xr, xi);
    dft16_layer2<-1>(xr, xi);
    { float2 v; v.x = xr[0]; v.y = xi[0]; buf[P(t)] = v; }
#pragma unroll
    for (int r = 1; r < 16; ++r) {
        float2 w = tw4096[r * 256 + t];
        float yr = xr[PERM(r)], yi = xi[PERM(r)];
        cmul(yr, yi, w.x, w.y);
        float2 v; v.x = yr; v.y = yi;
        buf[P(t + 256 * r)] = v;
    }
    __syncthreads();

    // ---- Phase B: fwd L=256
    int g = t >> 4, j = t & 15;
    int base = g * 256 + j;
#pragma unroll
    for (int r = 0; r < 16; ++r) {
        float2 v = buf[P(base + 16 * r)];
        xr[r] = v.x; xi[r] = v.y;
    }
    dft16<-1>(xr, xi);
    { float2 v; v.x = xr[0]; v.y = xi[0]; buf[P(base)] = v; }
#pragma unroll
    for (int r = 1; r < 16; ++r) {
        float2 w = tw256[r * 16 + j];
        float yr = xr[PERM(r)], yi = xi[PERM(r)];
        cmul(yr, yi, w.x, w.y);
        float2 v; v.x = yr; v.y = yi;
        buf[P(base + 16 * r)] = v;
    }
    __syncthreads();

    // ---- Phase C: fwd L=16 (no twiddle) + pointwise*V + inv L=16, in regs
    {
        int mb = 16 * t;
#pragma unroll
        for (int r = 0; r < 16; ++r) {
            float2 v = buf[P(mb + r)];
            xr[r] = v.x; xi[r] = v.y;
        }
        dft16<-1>(xr, xi);
        float yr2[16], yi2[16];
        const float4* Vv = (const float4*)(V2 + mb);
#pragma unroll
        for (int h = 0; h < 8; ++h) {
            float4 vv = Vv[h];
            int r = 2 * h;
            float ar = xr[PERM(r)], ai = xi[PERM(r)];
            yr2[r] = ar * vv.x - ai * vv.y;
            yi2[r] = ar * vv.y + ai * vv.x;
            r = 2 * h + 1;
            ar = xr[PERM(r)]; ai = xi[PERM(r)];
            yr2[r] = ar * vv.z - ai * vv.w;
            yi2[r] = ar * vv.w + ai * vv.z;
        }
        dft16<1>(yr2, yi2);
#pragma unroll
        for (int r = 0; r < 16; ++r) {
            float2 v; v.x = yr2[PERM(r)]; v.y = yi2[PERM(r)];
            buf[P(mb + r)] = v;
        }
    }
    __syncthreads();

    // ---- Phase D: inv L=256
#pragma unroll
    for (int r = 0; r < 16; ++r) {
        float2 v = buf[P(base + 16 * r)];
        xr[r] = v.x; xi[r] = v.y;
    }
#pragma unroll
    for (int r = 1; r < 16; ++r) {
        float2 w = tw256[r * 16 + j];
        cmulc(xr[r], xi[r], w.x, w.y);
    }
    dft16<1>(xr, xi);
#pragma unroll
    for (int r = 0; r < 16; ++r) {
        float2 v; v.x = xr[PERM(r)]; v.y = xi[PERM(r)];
        buf[P(base + 16 * r)] = v;
    }
    __syncthreads();

    // ---- Phase E: inv L=4096, pruned output (k<2048) straight to global
#pragma unroll
    for (int r = 0; r < 16; ++r) {
        float2 v = buf[P(t + 256 * r)];
        xr[r] = v.x; xi[r] = v.y;
    }
#pragma unroll
    for (int r = 1; r < 16; ++r) {
        float2 w = tw4096[r * 256 + t];
        cmulc(xr[r], xi[r], w.x, w.y);
    }
    dft16_layer1<1>(xr, xi);
    dft16_twiddle<1>(xr, xi);
    float* ob = out + ((size_t)b * N_) * E_ + e0;
#pragma unroll
    for (int k1 = 0; k1 < 4; ++k1) {
        float a0r = xr[4 * k1],     a0i = xi[4 * k1];
        float a1r = xr[4 * k1 + 1], a1i = xi[4 * k1 + 1];
        float a2r = xr[4 * k1 + 2], a2i = xi[4 * k1 + 2];
        float a3r = xr[4 * k1 + 3], a3i = xi[4 * k1 + 3];
        float t0r = a0r + a2r, t0i = a0i + a2i;
        float t1r = a0r - a2r, t1i = a0i - a2i;
        float t2r = a1r + a3r, t2i = a1i + a3i;
        float t3r = a1r - a3r, t3i = a1i - a3i;
        float2 v0; v0.x = t0r + t2r; v0.y = t0i + t2i;           // k = t+256*k1
        float2 v1; v1.x = t1r - t3i; v1.y = t1i + t3r;           // k = t+256*(k1+4)
        *(float2*)(ob + (size_t)(t + 256 * k1) * E_)       = v0;
        *(float2*)(ob + (size_t)(t + 256 * (k1 + 4)) * E_) = v1;
    }
}

// ---------------- fallback (ws too small): direct fp32 dot -------------------
__global__ __launch_bounds__(256) void naive_toep(const float* __restrict__ x,
                                                  const float* __restrict__ pos,
                                                  const float* __restrict__ zero,
                                                  const float* __restrict__ neg,
                                                  float* __restrict__ out) {
    int bid = blockIdx.x;
    int e   = (bid & 3) * 256 + threadIdx.x;
    int k   = (bid >> 2) & (N_ - 1);
    int b   = bid >> 13;
    float zv = zero[0];
    float acc = 0.f;
    const float* xb = x + (size_t)b * N_ * E_ + e;
    for (int jj = 0; jj < N_; ++jj) {
        float c = (jj < k) ? pos[k - jj - 1] : (jj == k) ? zv : neg[N_ - 1 - jj + k];
        acc += c * xb[(size_t)jj * E_];
    }
    out[((size_t)(b * N_ + k)) * E_ + e] = acc;
}

extern "C" void kernel_launch(void* const* d_in, const int* in_sizes, int n_in,
                              void* d_out, int out_size, void* d_ws, size_t ws_size,
                              hipStream_t stream) {
    const float* x    = (const float*)d_in[0];
    const float* pos  = (const float*)d_in[1];
    const float* zero = (const float*)d_in[2];
    const float* neg  = (const float*)d_in[3];
    float* out = (float*)d_out;

    const size_t needX = (size_t)B_ * E_ * N_ * sizeof(unsigned short);   // 32 MiB
    const size_t need  = needX + (2 * (size_t)NF + 256) * sizeof(float2);
    if (ws_size >= need) {
        unsigned short* xT = (unsigned short*)d_ws;
        float2* tw4096 = (float2*)((char*)d_ws + needX);
        float2* tw256  = tw4096 + NF;
        float2* V2     = tw256 + 256;
        prep<<<18 + 4096, 256, 0, stream>>>(x, pos, zero, neg, xT, tw4096, tw256, V2);
        fft_conv<<<4096, 256, 0, stream>>>(xT, tw4096, tw256, V2, out);
    } else {
        naive_toep<<<65536, 256, 0, stream>>>(x, pos, zero, neg, out);
    }
}

// Round 7
// 197.794 us; speedup vs baseline: 1.6560x; 1.4087x over previous
//
#include <hip/hip_runtime.h>
#include <stdint.h>

// Toeplitz matvec = circular conv via batched 4096-pt radix-16 FFT (3 stages).
// Per block: TWO real columns packed z = x[:,e0] + i*x[:,e0+1] (conv is
// real-linear -> out_e0 = Re, out_e1 = Im).
// v7: R6 minus the launch-bounds spill trigger. R5/R6's __launch_bounds__
// (256,5) forced VGPR=48 -> scratch spills -> +350MB HBM traffic (dur ==
// (FETCH+WRITE)/BW). Plain bounds (R4 compiled clean at 64 VGPR) + Phase C
// made in-place (PERM is an involution -> pair-swap pointwise, kills the
// second 32-float array = the register high-water mark). LDS exactly 32KB:
// 5 blocks/CU if VGPR<=96, else 4. Fused single-launch prep kept.
// ws: xT bf16[8][1024][2048] (32MiB) + tw4096 f2[4096] + tw256 f2[256] + V2 f2[4096].

#define B_ 8
#define N_ 2048
#define NF 4096
#define E_ 1024

// Bank swizzle (b64 accesses: bank-pair = idx mod 32). Patterns per wave:
//  A/E: n=t+256r; B/D: n=256g+16r+j; C: n=16t+r.
// low4 ^= n4-7 ^ n8-11, bit4 ^= n9 => every pattern ~2 lanes/bank-pair.
__device__ __forceinline__ int P(int n) {
    return n ^ ((n >> 4) & 15) ^ ((n >> 8) & 15) ^ (((n >> 9) & 1) << 4);
}
#define PERM(r) ((((r) & 3) << 2) | ((r) >> 2))   // DFT16 reg<->index transpose (involution)

__device__ __forceinline__ unsigned short f32_to_bf16_rne(float f) {
    union { float f; unsigned int u; } cv; cv.f = f;
    unsigned int u = cv.u;
    u += 0x7fffu + ((u >> 16) & 1u);
    return (unsigned short)(u >> 16);
}
__device__ __forceinline__ float bf16_to_f32(unsigned short u) {
    union { unsigned int u; float f; } cv; cv.u = ((unsigned int)u) << 16; return cv.f;
}
__device__ __forceinline__ void cmul(float& ar, float& ai, float br, float bi) {
    float t = ar * br - ai * bi; ai = ar * bi + ai * br; ar = t;
}
__device__ __forceinline__ void cmulc(float& ar, float& ai, float br, float bi) {
    float t = ar * br + ai * bi; ai = ai * br - ar * bi; ar = t;   // a *= conj(b)
}

__device__ __forceinline__ void dft4(float& x0r, float& x0i, float& x1r, float& x1i,
                                     float& x2r, float& x2i, float& x3r, float& x3i,
                                     float sg) {
    float t0r = x0r + x2r, t0i = x0i + x2i;
    float t1r = x0r - x2r, t1i = x0i - x2i;
    float t2r = x1r + x3r, t2i = x1i + x3i;
    float t3r = x1r - x3r, t3i = x1i - x3i;
    x0r = t0r + t2r; x0i = t0i + t2i;
    x2r = t0r - t2r; x2i = t0i - t2i;
    x1r = t1r - sg * t3i; x1i = t1i + sg * t3r;
    x3r = t1r + sg * t3i; x3i = t1i - sg * t3r;
}

template<int SG>
__device__ __forceinline__ void dft16_layer1(float* xr, float* xi) {
    const float sg = (float)SG;
#pragma unroll
    for (int n0 = 0; n0 < 4; ++n0)
        dft4(xr[n0], xi[n0], xr[n0 + 4], xi[n0 + 4],
             xr[n0 + 8], xi[n0 + 8], xr[n0 + 12], xi[n0 + 12], sg);
}
// upper 8 inputs (slots 8..15) known zero
template<int SG>
__device__ __forceinline__ void dft16_layer1_pad(float* xr, float* xi) {
    const float sg = (float)SG;
#pragma unroll
    for (int n0 = 0; n0 < 4; ++n0) {
        float ar = xr[n0], ai = xi[n0], br = xr[n0 + 4], bi = xi[n0 + 4];
        xr[n0]      = ar + br;       xi[n0]      = ai + bi;
        xr[n0 + 4]  = ar - sg * bi;  xi[n0 + 4]  = ai + sg * br;
        xr[n0 + 8]  = ar - br;       xi[n0 + 8]  = ai - bi;
        xr[n0 + 12] = ar + sg * bi;  xi[n0 + 12] = ai - sg * br;
    }
}
template<int SG>
__device__ __forceinline__ void dft16_twiddle(float* xr, float* xi) {
    const float sg = (float)SG;
    const float C1 = 0.923879532511286756f;
    const float S1 = 0.382683432365089772f;
    const float H  = 0.707106781186547524f;
    cmul(xr[5],  xi[5],  C1,  sg * S1);
    cmul(xr[9],  xi[9],  H,   sg * H);
    cmul(xr[13], xi[13], S1,  sg * C1);
    cmul(xr[6],  xi[6],  H,   sg * H);
    cmul(xr[10], xi[10], 0.f, sg);
    cmul(xr[14], xi[14], -H,  sg * H);
    cmul(xr[7],  xi[7],  S1,  sg * C1);
    cmul(xr[11], xi[11], -H,  sg * H);
    cmul(xr[15], xi[15], -C1, -sg * S1);
}
template<int SG>
__device__ __forceinline__ void dft16_layer2(float* xr, float* xi) {
    const float sg = (float)SG;
#pragma unroll
    for (int k1 = 0; k1 < 4; ++k1)
        dft4(xr[4 * k1], xi[4 * k1], xr[4 * k1 + 1], xi[4 * k1 + 1],
             xr[4 * k1 + 2], xi[4 * k1 + 2], xr[4 * k1 + 3], xi[4 * k1 + 3], sg);
}
template<int SG>
__device__ __forceinline__ void dft16(float* xr, float* xi) {
    dft16_layer1<SG>(xr, xi);
    dft16_twiddle<SG>(xr, xi);
    dft16_layer2<SG>(xr, xi);
}

// forward radix-16 stage with inline sincos twiddles (V build only, 1 block)
template<int L>
__device__ __forceinline__ void fwd_stage_sincos(float2* buf, int t) {
    constexpr int Lq = L / 16;
    int g = t / Lq;
    int j = t - g * Lq;
    int base = g * L + j;
    const float TPI = -6.28318530717958647692f;
    float xr[16], xi[16];
#pragma unroll
    for (int r = 0; r < 16; ++r) {
        float2 v = buf[P(base + r * Lq)];
        xr[r] = v.x; xi[r] = v.y;
    }
    dft16<-1>(xr, xi);
    { float2 v; v.x = xr[0]; v.y = xi[0]; buf[P(base)] = v; }
#pragma unroll
    for (int r = 1; r < 16; ++r) {
        float s, c;
        __sincosf(TPI * (float)(j * r) * (1.f / (float)L), &s, &c);
        float yr = xr[PERM(r)], yi = xi[PERM(r)];
        cmul(yr, yi, c, s);
        float2 v; v.x = yr; v.y = yi;
        buf[P(base + r * Lq)] = v;
    }
}

// ---------------- prep: tables + V + transpose, single launch ----------------
// blk 0..15 : tw4096[r*256+j] = cis(-2pi r j/4096), r=blk
// blk 16    : tw256[r*16+j]   = cis(-2pi r j/256)
// blk 17    : V2 = DIF(a)/4096, raw digit-reversed slots
// blk 18+   : x [b][j][e] fp32 -> xT [b][e][j] bf16, 64x64 tiles
__global__ __launch_bounds__(256) void prep(const float* __restrict__ x,
                                            const float* __restrict__ pos,
                                            const float* __restrict__ zero,
                                            const float* __restrict__ neg,
                                            unsigned short* __restrict__ xT,
                                            float2* __restrict__ tw4096,
                                            float2* __restrict__ tw256,
                                            float2* __restrict__ V2) {
    __shared__ __align__(16) char smraw[32768];
    const float TPI = -6.28318530717958647692f;
    int blk = blockIdx.x, t = threadIdx.x;
    if (blk < 16) {
        float s, c;
        __sincosf(TPI * (float)(blk * t) * (1.f / 4096.f), &s, &c);
        float2 v; v.x = c; v.y = s;
        tw4096[blk * 256 + t] = v;
    } else if (blk == 16) {
        int r = t >> 4, j = t & 15;
        float s, c;
        __sincosf(TPI * (float)(r * j) * (1.f / 256.f), &s, &c);
        float2 v; v.x = c; v.y = s;
        tw256[t] = v;
    } else if (blk == 17) {
        float2* buf = (float2*)smraw;
#pragma unroll
        for (int it = 0; it < 16; ++it) {
            int n = t + 256 * it;
            float v;
            if (n == 0) v = zero[0];
            else if (n < N_) v = pos[n - 1];
            else if (n == N_) v = zero[0];
            else v = neg[n - (N_ + 1)];
            float2 cc; cc.x = v; cc.y = 0.f;
            buf[P(n)] = cc;
        }
        __syncthreads();
        fwd_stage_sincos<4096>(buf, t); __syncthreads();
        fwd_stage_sincos<256>(buf, t);  __syncthreads();
        fwd_stage_sincos<16>(buf, t);   __syncthreads();
        const float s = 1.f / (float)NF;
#pragma unroll
        for (int it = 0; it < 16; ++it) {
            int n = t + 256 * it;
            float2 c = buf[P(n)];
            c.x *= s; c.y *= s;
            V2[n] = c;
        }
    } else {
        float (*tile)[66] = (float (*)[66])smraw;    // 64*66*4 = 16.9 KB
        int tid = blk - 18;
        int e0 = (tid & 15) * 64;
        int j0 = ((tid >> 4) & 31) * 64;
        int b  = tid >> 9;
        int e4 = t & 15, jr = t >> 4;
#pragma unroll
        for (int it = 0; it < 4; ++it) {
            int j = jr + it * 16;
            const float4 v = *(const float4*)(x + ((size_t)(b * N_ + j0 + j) * E_) + e0 + e4 * 4);
            tile[e4 * 4 + 0][j] = v.x;
            tile[e4 * 4 + 1][j] = v.y;
            tile[e4 * 4 + 2][j] = v.z;
            tile[e4 * 4 + 3][j] = v.w;
        }
        __syncthreads();
        int j2 = (t & 31) * 2, er = t >> 5;
#pragma unroll
        for (int it = 0; it < 8; ++it) {
            int e = er + it * 8;
            float2 v = *(const float2*)&tile[e][j2];
            union { unsigned short s[2]; unsigned int u; } pk;
            pk.s[0] = f32_to_bf16_rne(v.x);
            pk.s[1] = f32_to_bf16_rne(v.y);
            *(unsigned int*)(xT + ((size_t)(b * E_ + e0 + e)) * N_ + j0 + j2) = pk.u;
        }
    }
}

// ---------------- main: FFT-conv, one column pair per block ------------------
__global__ __launch_bounds__(256) void fft_conv(const unsigned short* __restrict__ xT,
                                                const float2* __restrict__ tw4096,
                                                const float2* __restrict__ tw256,
                                                const float2* __restrict__ V2,
                                                float* __restrict__ out) {
    __shared__ float2 buf[NF];              // exactly 32 KB
    int t = threadIdx.x;
    int bid = blockIdx.x;
    int xcd = bid & 7;                      // e-adjacent blocks share an XCD
    int q = bid >> 3;
    int b = q >> 6;
    int e0 = (xcd * 64 + (q & 63)) * 2;

    const unsigned short* r0 = xT + ((size_t)(b * E_ + e0)) * N_;
    const unsigned short* r1 = r0 + N_;

    float xr[16], xi[16];

    // ---- Phase A: fwd L=4096 straight from xT (bf16 rows); slots 8..15 zero
#pragma unroll
    for (int r = 0; r < 8; ++r) {
        int n = t + 256 * r;
        xr[r] = bf16_to_f32(r0[n]);
        xi[r] = bf16_to_f32(r1[n]);
    }
#pragma unroll
    for (int r = 8; r < 16; ++r) { xr[r] = 0.f; xi[r] = 0.f; }
    dft16_layer1_pad<-1>(xr, xi);
    dft16_twiddle<-1>(xr, xi);
    dft16_layer2<-1>(xr, xi);
    { float2 v; v.x = xr[0]; v.y = xi[0]; buf[P(t)] = v; }
#pragma unroll
    for (int r = 1; r < 16; ++r) {
        float2 w = tw4096[r * 256 + t];
        float yr = xr[PERM(r)], yi = xi[PERM(r)];
        cmul(yr, yi, w.x, w.y);
        float2 v; v.x = yr; v.y = yi;
        buf[P(t + 256 * r)] = v;
    }
    __syncthreads();

    // ---- Phase B: fwd L=256
    int g = t >> 4, j = t & 15;
    int base = g * 256 + j;
#pragma unroll
    for (int r = 0; r < 16; ++r) {
        float2 v = buf[P(base + 16 * r)];
        xr[r] = v.x; xi[r] = v.y;
    }
    dft16<-1>(xr, xi);
    { float2 v; v.x = xr[0]; v.y = xi[0]; buf[P(base)] = v; }
#pragma unroll
    for (int r = 1; r < 16; ++r) {
        float2 w = tw256[r * 16 + j];
        float yr = xr[PERM(r)], yi = xi[PERM(r)];
        cmul(yr, yi, w.x, w.y);
        float2 v; v.x = yr; v.y = yi;
        buf[P(base + 16 * r)] = v;
    }
    __syncthreads();

    // ---- Phase C: fwd L=16 (no twiddle) + pointwise*V + inv L=16, IN PLACE
    {
        int mb = 16 * t;
#pragma unroll
        for (int r = 0; r < 16; ++r) {
            float2 v = buf[P(mb + r)];
            xr[r] = v.x; xi[r] = v.y;
        }
        dft16<-1>(xr, xi);
        // y[r] = x[PERM(r)] * V[r]; PERM involution -> pair swap, no 2nd array
#pragma unroll
        for (int r = 0; r < 16; ++r) {
            int p = PERM(r);
            if (p < r) continue;
            if (p == r) {
                float2 vv = V2[mb + r];
                float ar = xr[r], ai = xi[r];
                xr[r] = ar * vv.x - ai * vv.y;
                xi[r] = ar * vv.y + ai * vv.x;
            } else {
                float2 va = V2[mb + r], vb = V2[mb + p];
                float ar = xr[r], ai = xi[r], br = xr[p], bi = xi[p];
                xr[r] = br * va.x - bi * va.y;
                xi[r] = br * va.y + bi * va.x;
                xr[p] = ar * vb.x - ai * vb.y;
                xi[p] = ar * vb.y + ai * vb.x;
            }
        }
        dft16<1>(xr, xi);
#pragma unroll
        for (int r = 0; r < 16; ++r) {
            float2 v; v.x = xr[PERM(r)]; v.y = xi[PERM(r)];
            buf[P(mb + r)] = v;
        }
    }
    __syncthreads();

    // ---- Phase D: inv L=256
#pragma unroll
    for (int r = 0; r < 16; ++r) {
        float2 v = buf[P(base + 16 * r)];
        xr[r] = v.x; xi[r] = v.y;
    }
#pragma unroll
    for (int r = 1; r < 16; ++r) {
        float2 w = tw256[r * 16 + j];
        cmulc(xr[r], xi[r], w.x, w.y);
    }
    dft16<1>(xr, xi);
#pragma unroll
    for (int r = 0; r < 16; ++r) {
        float2 v; v.x = xr[PERM(r)]; v.y = xi[PERM(r)];
        buf[P(base + 16 * r)] = v;
    }
    __syncthreads();

    // ---- Phase E: inv L=4096, pruned output (k<2048) straight to global
#pragma unroll
    for (int r = 0; r < 16; ++r) {
        float2 v = buf[P(t + 256 * r)];
        xr[r] = v.x; xi[r] = v.y;
    }
#pragma unroll
    for (int r = 1; r < 16; ++r) {
        float2 w = tw4096[r * 256 + t];
        cmulc(xr[r], xi[r], w.x, w.y);
    }
    dft16_layer1<1>(xr, xi);
    dft16_twiddle<1>(xr, xi);
    float* ob = out + ((size_t)b * N_) * E_ + e0;
#pragma unroll
    for (int k1 = 0; k1 < 4; ++k1) {
        float a0r = xr[4 * k1],     a0i = xi[4 * k1];
        float a1r = xr[4 * k1 + 1], a1i = xi[4 * k1 + 1];
        float a2r = xr[4 * k1 + 2], a2i = xi[4 * k1 + 2];
        float a3r = xr[4 * k1 + 3], a3i = xi[4 * k1 + 3];
        float t0r = a0r + a2r, t0i = a0i + a2i;
        float t1r = a0r - a2r, t1i = a0i - a2i;
        float t2r = a1r + a3r, t2i = a1i + a3i;
        float t3r = a1r - a3r, t3i = a1i - a3i;
        float2 v0; v0.x = t0r + t2r; v0.y = t0i + t2i;           // k = t+256*k1
        float2 v1; v1.x = t1r - t3i; v1.y = t1i + t3r;           // k = t+256*(k1+4)
        *(float2*)(ob + (size_t)(t + 256 * k1) * E_)       = v0;
        *(float2*)(ob + (size_t)(t + 256 * (k1 + 4)) * E_) = v1;
    }
}

// ---------------- fallback (ws too small): direct fp32 dot -------------------
__global__ __launch_bounds__(256) void naive_toep(const float* __restrict__ x,
                                                  const float* __restrict__ pos,
                                                  const float* __restrict__ zero,
                                                  const float* __restrict__ neg,
                                                  float* __restrict__ out) {
    int bid = blockIdx.x;
    int e   = (bid & 3) * 256 + threadIdx.x;
    int k   = (bid >> 2) & (N_ - 1);
    int b   = bid >> 13;
    float zv = zero[0];
    float acc = 0.f;
    const float* xb = x + (size_t)b * N_ * E_ + e;
    for (int jj = 0; jj < N_; ++jj) {
        float c = (jj < k) ? pos[k - jj - 1] : (jj == k) ? zv : neg[N_ - 1 - jj + k];
        acc += c * xb[(size_t)jj * E_];
    }
    out[((size_t)(b * N_ + k)) * E_ + e] = acc;
}

extern "C" void kernel_launch(void* const* d_in, const int* in_sizes, int n_in,
                              void* d_out, int out_size, void* d_ws, size_t ws_size,
                              hipStream_t stream) {
    const float* x    = (const float*)d_in[0];
    const float* pos  = (const float*)d_in[1];
    const float* zero = (const float*)d_in[2];
    const float* neg  = (const float*)d_in[3];
    float* out = (float*)d_out;

    const size_t needX = (size_t)B_ * E_ * N_ * sizeof(unsigned short);   // 32 MiB
    const size_t need  = needX + (2 * (size_t)NF + 256) * sizeof(float2);
    if (ws_size >= need) {
        unsigned short* xT = (unsigned short*)d_ws;
        float2* tw4096 = (float2*)((char*)d_ws + needX);
        float2* tw256  = tw4096 + NF;
        float2* V2     = tw256 + 256;
        prep<<<18 + 4096, 256, 0, stream>>>(x, pos, zero, neg, xT, tw4096, tw256, V2);
        fft_conv<<<4096, 256, 0, stream>>>(xT, tw4096, tw256, V2, out);
    } else {
        naive_toep<<<65536, 256, 0, stream>>>(x, pos, zero, neg, out);
    }
}

// Round 8
// 194.574 us; speedup vs baseline: 1.6835x; 1.0165x over previous
//
#include <hip/hip_runtime.h>
#include <stdint.h>

// Toeplitz matvec = circular conv via batched 4096-pt radix-16 FFT (3 stages).
// Per block: TWO real columns packed z = x[:,e0] + i*x[:,e0+1] (conv is
// real-linear -> out_e0 = Re, out_e1 = Im).
// v8 = R4 codegen + R7 LDS: Phase C reverted to the two-array form that
// compiled to VGPR=64 in R4 (R7's in-place pair-swap raised it to 84 ->
// occupancy 35->27%); LDS kept at exactly 32768B (R7) so the LDS cap is
// 5 blocks/CU and VGPR<=64 makes it binding: 20 waves/CU vs R4's 16.
// Kernel is latency-bound (VALU 43%, HBM 11%, conflicts 2%) -> occupancy
// is the lever. No min-waves launch bound (R5/R6 showed it forces spills).
// ws: xT bf16[8][1024][2048] (32MiB) + tw4096 f2[4096] + tw256 f2[256] + V2 f2[4096].

#define B_ 8
#define N_ 2048
#define NF 4096
#define E_ 1024

// Bank swizzle (b64 accesses: bank-pair = idx mod 32). Patterns per wave:
//  A/E: n=t+256r; B/D: n=256g+16r+j; C: n=16t+r.
// low4 ^= n4-7 ^ n8-11, bit4 ^= n9 => every pattern ~2 lanes/bank-pair.
__device__ __forceinline__ int P(int n) {
    return n ^ ((n >> 4) & 15) ^ ((n >> 8) & 15) ^ (((n >> 9) & 1) << 4);
}
#define PERM(r) ((((r) & 3) << 2) | ((r) >> 2))   // DFT16 reg<->index transpose

__device__ __forceinline__ unsigned short f32_to_bf16_rne(float f) {
    union { float f; unsigned int u; } cv; cv.f = f;
    unsigned int u = cv.u;
    u += 0x7fffu + ((u >> 16) & 1u);
    return (unsigned short)(u >> 16);
}
__device__ __forceinline__ float bf16_to_f32(unsigned short u) {
    union { unsigned int u; float f; } cv; cv.u = ((unsigned int)u) << 16; return cv.f;
}
__device__ __forceinline__ void cmul(float& ar, float& ai, float br, float bi) {
    float t = ar * br - ai * bi; ai = ar * bi + ai * br; ar = t;
}
__device__ __forceinline__ void cmulc(float& ar, float& ai, float br, float bi) {
    float t = ar * br + ai * bi; ai = ai * br - ar * bi; ar = t;   // a *= conj(b)
}

__device__ __forceinline__ void dft4(float& x0r, float& x0i, float& x1r, float& x1i,
                                     float& x2r, float& x2i, float& x3r, float& x3i,
                                     float sg) {
    float t0r = x0r + x2r, t0i = x0i + x2i;
    float t1r = x0r - x2r, t1i = x0i - x2i;
    float t2r = x1r + x3r, t2i = x1i + x3i;
    float t3r = x1r - x3r, t3i = x1i - x3i;
    x0r = t0r + t2r; x0i = t0i + t2i;
    x2r = t0r - t2r; x2i = t0i - t2i;
    x1r = t1r - sg * t3i; x1i = t1i + sg * t3r;
    x3r = t1r + sg * t3i; x3i = t1i - sg * t3r;
}

template<int SG>
__device__ __forceinline__ void dft16_layer1(float* xr, float* xi) {
    const float sg = (float)SG;
#pragma unroll
    for (int n0 = 0; n0 < 4; ++n0)
        dft4(xr[n0], xi[n0], xr[n0 + 4], xi[n0 + 4],
             xr[n0 + 8], xi[n0 + 8], xr[n0 + 12], xi[n0 + 12], sg);
}
// upper 8 inputs (slots 8..15) known zero
template<int SG>
__device__ __forceinline__ void dft16_layer1_pad(float* xr, float* xi) {
    const float sg = (float)SG;
#pragma unroll
    for (int n0 = 0; n0 < 4; ++n0) {
        float ar = xr[n0], ai = xi[n0], br = xr[n0 + 4], bi = xi[n0 + 4];
        xr[n0]      = ar + br;       xi[n0]      = ai + bi;
        xr[n0 + 4]  = ar - sg * bi;  xi[n0 + 4]  = ai + sg * br;
        xr[n0 + 8]  = ar - br;       xi[n0 + 8]  = ai - bi;
        xr[n0 + 12] = ar + sg * bi;  xi[n0 + 12] = ai - sg * br;
    }
}
template<int SG>
__device__ __forceinline__ void dft16_twiddle(float* xr, float* xi) {
    const float sg = (float)SG;
    const float C1 = 0.923879532511286756f;
    const float S1 = 0.382683432365089772f;
    const float H  = 0.707106781186547524f;
    cmul(xr[5],  xi[5],  C1,  sg * S1);
    cmul(xr[9],  xi[9],  H,   sg * H);
    cmul(xr[13], xi[13], S1,  sg * C1);
    cmul(xr[6],  xi[6],  H,   sg * H);
    cmul(xr[10], xi[10], 0.f, sg);
    cmul(xr[14], xi[14], -H,  sg * H);
    cmul(xr[7],  xi[7],  S1,  sg * C1);
    cmul(xr[11], xi[11], -H,  sg * H);
    cmul(xr[15], xi[15], -C1, -sg * S1);
}
template<int SG>
__device__ __forceinline__ void dft16_layer2(float* xr, float* xi) {
    const float sg = (float)SG;
#pragma unroll
    for (int k1 = 0; k1 < 4; ++k1)
        dft4(xr[4 * k1], xi[4 * k1], xr[4 * k1 + 1], xi[4 * k1 + 1],
             xr[4 * k1 + 2], xi[4 * k1 + 2], xr[4 * k1 + 3], xi[4 * k1 + 3], sg);
}
template<int SG>
__device__ __forceinline__ void dft16(float* xr, float* xi) {
    dft16_layer1<SG>(xr, xi);
    dft16_twiddle<SG>(xr, xi);
    dft16_layer2<SG>(xr, xi);
}

// forward radix-16 stage with inline sincos twiddles (V build only, 1 block)
template<int L>
__device__ __forceinline__ void fwd_stage_sincos(float2* buf, int t) {
    constexpr int Lq = L / 16;
    int g = t / Lq;
    int j = t - g * Lq;
    int base = g * L + j;
    const float TPI = -6.28318530717958647692f;
    float xr[16], xi[16];
#pragma unroll
    for (int r = 0; r < 16; ++r) {
        float2 v = buf[P(base + r * Lq)];
        xr[r] = v.x; xi[r] = v.y;
    }
    dft16<-1>(xr, xi);
    { float2 v; v.x = xr[0]; v.y = xi[0]; buf[P(base)] = v; }
#pragma unroll
    for (int r = 1; r < 16; ++r) {
        float s, c;
        __sincosf(TPI * (float)(j * r) * (1.f / (float)L), &s, &c);
        float yr = xr[PERM(r)], yi = xi[PERM(r)];
        cmul(yr, yi, c, s);
        float2 v; v.x = yr; v.y = yi;
        buf[P(base + r * Lq)] = v;
    }
}

// ---------------- prep: tables + V + transpose, single launch ----------------
// blk 0..15 : tw4096[r*256+j] = cis(-2pi r j/4096), r=blk
// blk 16    : tw256[r*16+j]   = cis(-2pi r j/256)
// blk 17    : V2 = DIF(a)/4096, raw digit-reversed slots
// blk 18+   : x [b][j][e] fp32 -> xT [b][e][j] bf16, 64x64 tiles
__global__ __launch_bounds__(256) void prep(const float* __restrict__ x,
                                            const float* __restrict__ pos,
                                            const float* __restrict__ zero,
                                            const float* __restrict__ neg,
                                            unsigned short* __restrict__ xT,
                                            float2* __restrict__ tw4096,
                                            float2* __restrict__ tw256,
                                            float2* __restrict__ V2) {
    __shared__ __align__(16) char smraw[32768];
    const float TPI = -6.28318530717958647692f;
    int blk = blockIdx.x, t = threadIdx.x;
    if (blk < 16) {
        float s, c;
        __sincosf(TPI * (float)(blk * t) * (1.f / 4096.f), &s, &c);
        float2 v; v.x = c; v.y = s;
        tw4096[blk * 256 + t] = v;
    } else if (blk == 16) {
        int r = t >> 4, j = t & 15;
        float s, c;
        __sincosf(TPI * (float)(r * j) * (1.f / 256.f), &s, &c);
        float2 v; v.x = c; v.y = s;
        tw256[t] = v;
    } else if (blk == 17) {
        float2* buf = (float2*)smraw;
#pragma unroll
        for (int it = 0; it < 16; ++it) {
            int n = t + 256 * it;
            float v;
            if (n == 0) v = zero[0];
            else if (n < N_) v = pos[n - 1];
            else if (n == N_) v = zero[0];
            else v = neg[n - (N_ + 1)];
            float2 cc; cc.x = v; cc.y = 0.f;
            buf[P(n)] = cc;
        }
        __syncthreads();
        fwd_stage_sincos<4096>(buf, t); __syncthreads();
        fwd_stage_sincos<256>(buf, t);  __syncthreads();
        fwd_stage_sincos<16>(buf, t);   __syncthreads();
        const float s = 1.f / (float)NF;
#pragma unroll
        for (int it = 0; it < 16; ++it) {
            int n = t + 256 * it;
            float2 c = buf[P(n)];
            c.x *= s; c.y *= s;
            V2[n] = c;
        }
    } else {
        float (*tile)[66] = (float (*)[66])smraw;    // 64*66*4 = 16.9 KB
        int tid = blk - 18;
        int e0 = (tid & 15) * 64;
        int j0 = ((tid >> 4) & 31) * 64;
        int b  = tid >> 9;
        int e4 = t & 15, jr = t >> 4;
#pragma unroll
        for (int it = 0; it < 4; ++it) {
            int j = jr + it * 16;
            const float4 v = *(const float4*)(x + ((size_t)(b * N_ + j0 + j) * E_) + e0 + e4 * 4);
            tile[e4 * 4 + 0][j] = v.x;
            tile[e4 * 4 + 1][j] = v.y;
            tile[e4 * 4 + 2][j] = v.z;
            tile[e4 * 4 + 3][j] = v.w;
        }
        __syncthreads();
        int j2 = (t & 31) * 2, er = t >> 5;
#pragma unroll
        for (int it = 0; it < 8; ++it) {
            int e = er + it * 8;
            float2 v = *(const float2*)&tile[e][j2];
            union { unsigned short s[2]; unsigned int u; } pk;
            pk.s[0] = f32_to_bf16_rne(v.x);
            pk.s[1] = f32_to_bf16_rne(v.y);
            *(unsigned int*)(xT + ((size_t)(b * E_ + e0 + e)) * N_ + j0 + j2) = pk.u;
        }
    }
}

// ---------------- main: FFT-conv, one column pair per block ------------------
__global__ __launch_bounds__(256) void fft_conv(const unsigned short* __restrict__ xT,
                                                const float2* __restrict__ tw4096,
                                                const float2* __restrict__ tw256,
                                                const float2* __restrict__ V2,
                                                float* __restrict__ out) {
    __shared__ float2 buf[NF];              // exactly 32 KB -> 5 blocks/CU
    int t = threadIdx.x;
    int bid = blockIdx.x;
    int xcd = bid & 7;                      // e-adjacent blocks share an XCD
    int q = bid >> 3;
    int b = q >> 6;
    int e0 = (xcd * 64 + (q & 63)) * 2;

    const unsigned short* r0 = xT + ((size_t)(b * E_ + e0)) * N_;
    const unsigned short* r1 = r0 + N_;

    float xr[16], xi[16];

    // ---- Phase A: fwd L=4096 straight from xT (bf16 rows); slots 8..15 zero
#pragma unroll
    for (int r = 0; r < 8; ++r) {
        int n = t + 256 * r;
        xr[r] = bf16_to_f32(r0[n]);
        xi[r] = bf16_to_f32(r1[n]);
    }
#pragma unroll
    for (int r = 8; r < 16; ++r) { xr[r] = 0.f; xi[r] = 0.f; }
    dft16_layer1_pad<-1>(xr, xi);
    dft16_twiddle<-1>(xr, xi);
    dft16_layer2<-1>(xr, xi);
    { float2 v; v.x = xr[0]; v.y = xi[0]; buf[P(t)] = v; }
#pragma unroll
    for (int r = 1; r < 16; ++r) {
        float2 w = tw4096[r * 256 + t];
        float yr = xr[PERM(r)], yi = xi[PERM(r)];
        cmul(yr, yi, w.x, w.y);
        float2 v; v.x = yr; v.y = yi;
        buf[P(t + 256 * r)] = v;
    }
    __syncthreads();

    // ---- Phase B: fwd L=256
    int g = t >> 4, j = t & 15;
    int base = g * 256 + j;
#pragma unroll
    for (int r = 0; r < 16; ++r) {
        float2 v = buf[P(base + 16 * r)];
        xr[r] = v.x; xi[r] = v.y;
    }
    dft16<-1>(xr, xi);
    { float2 v; v.x = xr[0]; v.y = xi[0]; buf[P(base)] = v; }
#pragma unroll
    for (int r = 1; r < 16; ++r) {
        float2 w = tw256[r * 16 + j];
        float yr = xr[PERM(r)], yi = xi[PERM(r)];
        cmul(yr, yi, w.x, w.y);
        float2 v; v.x = yr; v.y = yi;
        buf[P(base + 16 * r)] = v;
    }
    __syncthreads();

    // ---- Phase C: fwd L=16 (no twiddle) + pointwise*V + inv L=16, in regs
    // (two-array form: compiled to VGPR=64 in R4; in-place variant was 84)
    {
        int mb = 16 * t;
#pragma unroll
        for (int r = 0; r < 16; ++r) {
            float2 v = buf[P(mb + r)];
            xr[r] = v.x; xi[r] = v.y;
        }
        dft16<-1>(xr, xi);
        float yr2[16], yi2[16];
        const float4* Vv = (const float4*)(V2 + mb);
#pragma unroll
        for (int h = 0; h < 8; ++h) {
            float4 vv = Vv[h];
            int r = 2 * h;
            float ar = xr[PERM(r)], ai = xi[PERM(r)];
            yr2[r] = ar * vv.x - ai * vv.y;
            yi2[r] = ar * vv.y + ai * vv.x;
            r = 2 * h + 1;
            ar = xr[PERM(r)]; ai = xi[PERM(r)];
            yr2[r] = ar * vv.z - ai * vv.w;
            yi2[r] = ar * vv.w + ai * vv.z;
        }
        dft16<1>(yr2, yi2);
#pragma unroll
        for (int r = 0; r < 16; ++r) {
            float2 v; v.x = yr2[PERM(r)]; v.y = yi2[PERM(r)];
            buf[P(mb + r)] = v;
        }
    }
    __syncthreads();

    // ---- Phase D: inv L=256
#pragma unroll
    for (int r = 0; r < 16; ++r) {
        float2 v = buf[P(base + 16 * r)];
        xr[r] = v.x; xi[r] = v.y;
    }
#pragma unroll
    for (int r = 1; r < 16; ++r) {
        float2 w = tw256[r * 16 + j];
        cmulc(xr[r], xi[r], w.x, w.y);
    }
    dft16<1>(xr, xi);
#pragma unroll
    for (int r = 0; r < 16; ++r) {
        float2 v; v.x = xr[PERM(r)]; v.y = xi[PERM(r)];
        buf[P(base + 16 * r)] = v;
    }
    __syncthreads();

    // ---- Phase E: inv L=4096, pruned output (k<2048) straight to global
#pragma unroll
    for (int r = 0; r < 16; ++r) {
        float2 v = buf[P(t + 256 * r)];
        xr[r] = v.x; xi[r] = v.y;
    }
#pragma unroll
    for (int r = 1; r < 16; ++r) {
        float2 w = tw4096[r * 256 + t];
        cmulc(xr[r], xi[r], w.x, w.y);
    }
    dft16_layer1<1>(xr, xi);
    dft16_twiddle<1>(xr, xi);
    float* ob = out + ((size_t)b * N_) * E_ + e0;
#pragma unroll
    for (int k1 = 0; k1 < 4; ++k1) {
        float a0r = xr[4 * k1],     a0i = xi[4 * k1];
        float a1r = xr[4 * k1 + 1], a1i = xi[4 * k1 + 1];
        float a2r = xr[4 * k1 + 2], a2i = xi[4 * k1 + 2];
        float a3r = xr[4 * k1 + 3], a3i = xi[4 * k1 + 3];
        float t0r = a0r + a2r, t0i = a0i + a2i;
        float t1r = a0r - a2r, t1i = a0i - a2i;
        float t2r = a1r + a3r, t2i = a1i + a3i;
        float t3r = a1r - a3r, t3i = a1i - a3i;
        float2 v0; v0.x = t0r + t2r; v0.y = t0i + t2i;           // k = t+256*k1
        float2 v1; v1.x = t1r - t3i; v1.y = t1i + t3r;           // k = t+256*(k1+4)
        *(float2*)(ob + (size_t)(t + 256 * k1) * E_)       = v0;
        *(float2*)(ob + (size_t)(t + 256 * (k1 + 4)) * E_) = v1;
    }
}

// ---------------- fallback (ws too small): direct fp32 dot -------------------
__global__ __launch_bounds__(256) void naive_toep(const float* __restrict__ x,
                                                  const float* __restrict__ pos,
                                                  const float* __restrict__ zero,
                                                  const float* __restrict__ neg,
                                                  float* __restrict__ out) {
    int bid = blockIdx.x;
    int e   = (bid & 3) * 256 + threadIdx.x;
    int k   = (bid >> 2) & (N_ - 1);
    int b   = bid >> 13;
    float zv = zero[0];
    float acc = 0.f;
    const float* xb = x + (size_t)b * N_ * E_ + e;
    for (int jj = 0; jj < N_; ++jj) {
        float c = (jj < k) ? pos[k - jj - 1] : (jj == k) ? zv : neg[N_ - 1 - jj + k];
        acc += c * xb[(size_t)jj * E_];
    }
    out[((size_t)(b * N_ + k)) * E_ + e] = acc;
}

extern "C" void kernel_launch(void* const* d_in, const int* in_sizes, int n_in,
                              void* d_out, int out_size, void* d_ws, size_t ws_size,
                              hipStream_t stream) {
    const float* x    = (const float*)d_in[0];
    const float* pos  = (const float*)d_in[1];
    const float* zero = (const float*)d_in[2];
    const float* neg  = (const float*)d_in[3];
    float* out = (float*)d_out;

    const size_t needX = (size_t)B_ * E_ * N_ * sizeof(unsigned short);   // 32 MiB
    const size_t need  = needX + (2 * (size_t)NF + 256) * sizeof(float2);
    if (ws_size >= need) {
        unsigned short* xT = (unsigned short*)d_ws;
        float2* tw4096 = (float2*)((char*)d_ws + needX);
        float2* tw256  = tw4096 + NF;
        float2* V2     = tw256 + 256;
        prep<<<18 + 4096, 256, 0, stream>>>(x, pos, zero, neg, xT, tw4096, tw256, V2);
        fft_conv<<<4096, 256, 0, stream>>>(xT, tw4096, tw256, V2, out);
    } else {
        naive_toep<<<65536, 256, 0, stream>>>(x, pos, zero, neg, out);
    }
}

// Round 9
// 177.028 us; speedup vs baseline: 1.8503x; 1.0991x over previous
//
#include <hip/hip_runtime.h>
#include <stdint.h>

// Toeplitz matvec = circular conv via batched 4096-pt radix-16 FFT (3 stages).
// v9: ILP=2 — each block runs TWO independent FFTs (two column-pairs, 4 cols),
// two 32KB LDS bufs (64KB -> 2 blocks/CU; R3-R8 showed occupancy 27-40% does
// not move duration -> kernel is dependency-stall bound, so per-thread ILP is
// the lever: every butterfly op has an independent twin to interleave).
// Twiddle/V loads shared across streams; input is e-pair-interleaved u32
// (one dword load = both columns of a stream at n); output float4 (4 cols).
// ws: xP u32[8][512][2048] (32MiB) + tw4096 f2[4096] + tw256 f2[256] + V2 f2[4096].

#define B_ 8
#define N_ 2048
#define NF 4096
#define E_ 1024

// Bank swizzle: all phase patterns land ~2 lanes/bank-pair (free, m136).
__device__ __forceinline__ int P(int n) {
    return n ^ ((n >> 4) & 15) ^ ((n >> 8) & 15) ^ (((n >> 9) & 1) << 4);
}
#define PERM(r) ((((r) & 3) << 2) | ((r) >> 2))   // DFT16 reg<->index transpose

__device__ __forceinline__ unsigned short f32_to_bf16_rne(float f) {
    union { float f; unsigned int u; } cv; cv.f = f;
    unsigned int u = cv.u;
    u += 0x7fffu + ((u >> 16) & 1u);
    return (unsigned short)(u >> 16);
}
__device__ __forceinline__ float bf16_to_f32(unsigned short u) {
    union { unsigned int u; float f; } cv; cv.u = ((unsigned int)u) << 16; return cv.f;
}
__device__ __forceinline__ void cmul(float& ar, float& ai, float br, float bi) {
    float t = ar * br - ai * bi; ai = ar * bi + ai * br; ar = t;
}
__device__ __forceinline__ void cmulc(float& ar, float& ai, float br, float bi) {
    float t = ar * br + ai * bi; ai = ai * br - ar * bi; ar = t;   // a *= conj(b)
}

__device__ __forceinline__ void dft4(float& x0r, float& x0i, float& x1r, float& x1i,
                                     float& x2r, float& x2i, float& x3r, float& x3i,
                                     float sg) {
    float t0r = x0r + x2r, t0i = x0i + x2i;
    float t1r = x0r - x2r, t1i = x0i - x2i;
    float t2r = x1r + x3r, t2i = x1i + x3i;
    float t3r = x1r - x3r, t3i = x1i - x3i;
    x0r = t0r + t2r; x0i = t0i + t2i;
    x2r = t0r - t2r; x2i = t0i - t2i;
    x1r = t1r - sg * t3i; x1i = t1i + sg * t3r;
    x3r = t1r + sg * t3i; x3i = t1i - sg * t3r;
}

template<int SG>
__device__ __forceinline__ void dft16_layer1(float* xr, float* xi) {
    const float sg = (float)SG;
#pragma unroll
    for (int n0 = 0; n0 < 4; ++n0)
        dft4(xr[n0], xi[n0], xr[n0 + 4], xi[n0 + 4],
             xr[n0 + 8], xi[n0 + 8], xr[n0 + 12], xi[n0 + 12], sg);
}
// upper 8 inputs (slots 8..15) known zero
template<int SG>
__device__ __forceinline__ void dft16_layer1_pad(float* xr, float* xi) {
    const float sg = (float)SG;
#pragma unroll
    for (int n0 = 0; n0 < 4; ++n0) {
        float ar = xr[n0], ai = xi[n0], br = xr[n0 + 4], bi = xi[n0 + 4];
        xr[n0]      = ar + br;       xi[n0]      = ai + bi;
        xr[n0 + 4]  = ar - sg * bi;  xi[n0 + 4]  = ai + sg * br;
        xr[n0 + 8]  = ar - br;       xi[n0 + 8]  = ai - bi;
        xr[n0 + 12] = ar + sg * bi;  xi[n0 + 12] = ai - sg * br;
    }
}
template<int SG>
__device__ __forceinline__ void dft16_twiddle(float* xr, float* xi) {
    const float sg = (float)SG;
    const float C1 = 0.923879532511286756f;
    const float S1 = 0.382683432365089772f;
    const float H  = 0.707106781186547524f;
    cmul(xr[5],  xi[5],  C1,  sg * S1);
    cmul(xr[9],  xi[9],  H,   sg * H);
    cmul(xr[13], xi[13], S1,  sg * C1);
    cmul(xr[6],  xi[6],  H,   sg * H);
    cmul(xr[10], xi[10], 0.f, sg);
    cmul(xr[14], xi[14], -H,  sg * H);
    cmul(xr[7],  xi[7],  S1,  sg * C1);
    cmul(xr[11], xi[11], -H,  sg * H);
    cmul(xr[15], xi[15], -C1, -sg * S1);
}
template<int SG>
__device__ __forceinline__ void dft16_layer2(float* xr, float* xi) {
    const float sg = (float)SG;
#pragma unroll
    for (int k1 = 0; k1 < 4; ++k1)
        dft4(xr[4 * k1], xi[4 * k1], xr[4 * k1 + 1], xi[4 * k1 + 1],
             xr[4 * k1 + 2], xi[4 * k1 + 2], xr[4 * k1 + 3], xi[4 * k1 + 3], sg);
}
template<int SG>
__device__ __forceinline__ void dft16(float* xr, float* xi) {
    dft16_layer1<SG>(xr, xi);
    dft16_twiddle<SG>(xr, xi);
    dft16_layer2<SG>(xr, xi);
}

// forward radix-16 stage with inline sincos twiddles (V build only, 1 block)
template<int L>
__device__ __forceinline__ void fwd_stage_sincos(float2* buf, int t) {
    constexpr int Lq = L / 16;
    int g = t / Lq;
    int j = t - g * Lq;
    int base = g * L + j;
    const float TPI = -6.28318530717958647692f;
    float xr[16], xi[16];
#pragma unroll
    for (int r = 0; r < 16; ++r) {
        float2 v = buf[P(base + r * Lq)];
        xr[r] = v.x; xi[r] = v.y;
    }
    dft16<-1>(xr, xi);
    { float2 v; v.x = xr[0]; v.y = xi[0]; buf[P(base)] = v; }
#pragma unroll
    for (int r = 1; r < 16; ++r) {
        float s, c;
        __sincosf(TPI * (float)(j * r) * (1.f / (float)L), &s, &c);
        float yr = xr[PERM(r)], yi = xi[PERM(r)];
        cmul(yr, yi, c, s);
        float2 v; v.x = yr; v.y = yi;
        buf[P(base + r * Lq)] = v;
    }
}

// ---------------- prep: tables + V + pair-interleaved transpose --------------
// blk 0..15 : tw4096[r*256+j] = cis(-2pi r j/4096), r=blk
// blk 16    : tw256[r*16+j]   = cis(-2pi r j/256)
// blk 17    : V2 = DIF(a)/4096, raw digit-reversed slots
// blk 18+   : x [b][j][e] fp32 -> xP [b][e/2][j] u32 = (bf16 e, bf16 e+1)
__global__ __launch_bounds__(256) void prep(const float* __restrict__ x,
                                            const float* __restrict__ pos,
                                            const float* __restrict__ zero,
                                            const float* __restrict__ neg,
                                            uint32_t* __restrict__ xP,
                                            float2* __restrict__ tw4096,
                                            float2* __restrict__ tw256,
                                            float2* __restrict__ V2) {
    __shared__ __align__(16) char smraw[32768];
    const float TPI = -6.28318530717958647692f;
    int blk = blockIdx.x, t = threadIdx.x;
    if (blk < 16) {
        float s, c;
        __sincosf(TPI * (float)(blk * t) * (1.f / 4096.f), &s, &c);
        float2 v; v.x = c; v.y = s;
        tw4096[blk * 256 + t] = v;
    } else if (blk == 16) {
        int r = t >> 4, j = t & 15;
        float s, c;
        __sincosf(TPI * (float)(r * j) * (1.f / 256.f), &s, &c);
        float2 v; v.x = c; v.y = s;
        tw256[t] = v;
    } else if (blk == 17) {
        float2* buf = (float2*)smraw;
#pragma unroll
        for (int it = 0; it < 16; ++it) {
            int n = t + 256 * it;
            float v;
            if (n == 0) v = zero[0];
            else if (n < N_) v = pos[n - 1];
            else if (n == N_) v = zero[0];
            else v = neg[n - (N_ + 1)];
            float2 cc; cc.x = v; cc.y = 0.f;
            buf[P(n)] = cc;
        }
        __syncthreads();
        fwd_stage_sincos<4096>(buf, t); __syncthreads();
        fwd_stage_sincos<256>(buf, t);  __syncthreads();
        fwd_stage_sincos<16>(buf, t);   __syncthreads();
        const float s = 1.f / (float)NF;
#pragma unroll
        for (int it = 0; it < 16; ++it) {
            int n = t + 256 * it;
            float2 c = buf[P(n)];
            c.x *= s; c.y *= s;
            V2[n] = c;
        }
    } else {
        float (*tile)[66] = (float (*)[66])smraw;    // 64*66*4 = 16.9 KB
        int tid = blk - 18;
        int e0 = (tid & 15) * 64;                    // e-tile base
        int j0 = ((tid >> 4) & 31) * 64;             // n-tile base
        int b  = tid >> 9;
        int e4 = t & 15, jr = t >> 4;
#pragma unroll
        for (int it = 0; it < 4; ++it) {
            int j = jr + it * 16;
            const float4 v = *(const float4*)(x + ((size_t)(b * N_ + j0 + j) * E_) + e0 + e4 * 4);
            tile[e4 * 4 + 0][j] = v.x;
            tile[e4 * 4 + 1][j] = v.y;
            tile[e4 * 4 + 2][j] = v.z;
            tile[e4 * 4 + 3][j] = v.w;
        }
        __syncthreads();
        int jj = t & 63, ur = t >> 6;                // ur 0..3
#pragma unroll
        for (int it = 0; it < 8; ++it) {
            int u = ur + it * 4;                     // pair-local 0..31
            union { unsigned short s[2]; uint32_t w; } pk;
            pk.s[0] = f32_to_bf16_rne(tile[2 * u][jj]);
            pk.s[1] = f32_to_bf16_rne(tile[2 * u + 1][jj]);
            xP[((size_t)(b * 512 + (e0 >> 1) + u)) * N_ + j0 + jj] = pk.w;
        }
    }
}

// ---------------- main: FFT-conv, TWO column pairs per block (ILP=2) ---------
__global__ __launch_bounds__(256) void fft_conv(const uint32_t* __restrict__ xP,
                                                const float2* __restrict__ tw4096,
                                                const float2* __restrict__ tw256,
                                                const float2* __restrict__ V2,
                                                float* __restrict__ out) {
    __shared__ float2 buf0[NF];
    __shared__ float2 buf1[NF];             // 64 KB total
    int t = threadIdx.x;
    int bid = blockIdx.x;                   // 2048
    int xcd = bid & 7;
    int q = bid >> 3;                       // 0..255
    int b = q >> 5;                         // 0..7
    int quad = xcd * 32 + (q & 31);         // 0..255 -> e0 = quad*4
    const uint32_t* g0 = xP + ((size_t)(b * 512 + quad * 2)) * N_;
    const uint32_t* g1 = g0 + N_;

    float x0r[16], x0i[16], x1r[16], x1i[16];

    // ---- Phase A: fwd L=4096 from global; slots 8..15 zero
#pragma unroll
    for (int r = 0; r < 8; ++r) {
        int n = t + 256 * r;
        uint32_t u0 = g0[n], u1 = g1[n];
        x0r[r] = bf16_to_f32((unsigned short)(u0 & 0xffff));
        x0i[r] = bf16_to_f32((unsigned short)(u0 >> 16));
        x1r[r] = bf16_to_f32((unsigned short)(u1 & 0xffff));
        x1i[r] = bf16_to_f32((unsigned short)(u1 >> 16));
    }
#pragma unroll
    for (int r = 8; r < 16; ++r) { x0r[r] = 0.f; x0i[r] = 0.f; x1r[r] = 0.f; x1i[r] = 0.f; }
    dft16_layer1_pad<-1>(x0r, x0i); dft16_layer1_pad<-1>(x1r, x1i);
    dft16_twiddle<-1>(x0r, x0i);    dft16_twiddle<-1>(x1r, x1i);
    dft16_layer2<-1>(x0r, x0i);     dft16_layer2<-1>(x1r, x1i);
    { float2 v; v.x = x0r[0]; v.y = x0i[0]; buf0[P(t)] = v;
      float2 w; w.x = x1r[0]; w.y = x1i[0]; buf1[P(t)] = w; }
#pragma unroll
    for (int r = 1; r < 16; ++r) {
        float2 w = tw4096[r * 256 + t];                 // shared twiddle
        int a = P(t + 256 * r);
        float y0r = x0r[PERM(r)], y0i = x0i[PERM(r)];
        cmul(y0r, y0i, w.x, w.y);
        float2 v0; v0.x = y0r; v0.y = y0i; buf0[a] = v0;
        float y1r = x1r[PERM(r)], y1i = x1i[PERM(r)];
        cmul(y1r, y1i, w.x, w.y);
        float2 v1; v1.x = y1r; v1.y = y1i; buf1[a] = v1;
    }
    __syncthreads();

    // ---- Phase B: fwd L=256
    int g = t >> 4, j = t & 15;
    int base = g * 256 + j;
#pragma unroll
    for (int r = 0; r < 16; ++r) {
        int a = P(base + 16 * r);
        float2 v0 = buf0[a]; x0r[r] = v0.x; x0i[r] = v0.y;
        float2 v1 = buf1[a]; x1r[r] = v1.x; x1i[r] = v1.y;
    }
    dft16<-1>(x0r, x0i); dft16<-1>(x1r, x1i);
    { float2 v; v.x = x0r[0]; v.y = x0i[0]; buf0[P(base)] = v;
      float2 w; w.x = x1r[0]; w.y = x1i[0]; buf1[P(base)] = w; }
#pragma unroll
    for (int r = 1; r < 16; ++r) {
        float2 w = tw256[r * 16 + j];
        int a = P(base + 16 * r);
        float y0r = x0r[PERM(r)], y0i = x0i[PERM(r)];
        cmul(y0r, y0i, w.x, w.y);
        float2 v0; v0.x = y0r; v0.y = y0i; buf0[a] = v0;
        float y1r = x1r[PERM(r)], y1i = x1i[PERM(r)];
        cmul(y1r, y1i, w.x, w.y);
        float2 v1; v1.x = y1r; v1.y = y1i; buf1[a] = v1;
    }
    __syncthreads();

    // ---- Phase C: fwd L=16 + pointwise*V (shared) + inv L=16, in place
    {
        int mb = 16 * t;
#pragma unroll
        for (int r = 0; r < 16; ++r) {
            int a = P(mb + r);
            float2 v0 = buf0[a]; x0r[r] = v0.x; x0i[r] = v0.y;
            float2 v1 = buf1[a]; x1r[r] = v1.x; x1i[r] = v1.y;
        }
        dft16<-1>(x0r, x0i); dft16<-1>(x1r, x1i);
        // y[r] = x[PERM(r)]*V[r]; PERM involution -> pair swap, V shared
#pragma unroll
        for (int r = 0; r < 16; ++r) {
            int p = PERM(r);
            if (p < r) continue;
            if (p == r) {
                float2 vv = V2[mb + r];
                float ar = x0r[r], ai = x0i[r];
                x0r[r] = ar * vv.x - ai * vv.y; x0i[r] = ar * vv.y + ai * vv.x;
                ar = x1r[r]; ai = x1i[r];
                x1r[r] = ar * vv.x - ai * vv.y; x1i[r] = ar * vv.y + ai * vv.x;
            } else {
                float2 va = V2[mb + r], vb = V2[mb + p];
                float ar = x0r[r], ai = x0i[r], br = x0r[p], bi = x0i[p];
                x0r[r] = br * va.x - bi * va.y; x0i[r] = br * va.y + bi * va.x;
                x0r[p] = ar * vb.x - ai * vb.y; x0i[p] = ar * vb.y + ai * vb.x;
                ar = x1r[r]; ai = x1i[r]; br = x1r[p]; bi = x1i[p];
                x1r[r] = br * va.x - bi * va.y; x1i[r] = br * va.y + bi * va.x;
                x1r[p] = ar * vb.x - ai * vb.y; x1i[p] = ar * vb.y + ai * vb.x;
            }
        }
        dft16<1>(x0r, x0i); dft16<1>(x1r, x1i);
#pragma unroll
        for (int r = 0; r < 16; ++r) {
            int a = P(mb + r);
            float2 v0; v0.x = x0r[PERM(r)]; v0.y = x0i[PERM(r)]; buf0[a] = v0;
            float2 v1; v1.x = x1r[PERM(r)]; v1.y = x1i[PERM(r)]; buf1[a] = v1;
        }
    }
    __syncthreads();

    // ---- Phase D: inv L=256
#pragma unroll
    for (int r = 0; r < 16; ++r) {
        int a = P(base + 16 * r);
        float2 v0 = buf0[a]; x0r[r] = v0.x; x0i[r] = v0.y;
        float2 v1 = buf1[a]; x1r[r] = v1.x; x1i[r] = v1.y;
    }
#pragma unroll
    for (int r = 1; r < 16; ++r) {
        float2 w = tw256[r * 16 + j];
        cmulc(x0r[r], x0i[r], w.x, w.y);
        cmulc(x1r[r], x1i[r], w.x, w.y);
    }
    dft16<1>(x0r, x0i); dft16<1>(x1r, x1i);
#pragma unroll
    for (int r = 0; r < 16; ++r) {
        int a = P(base + 16 * r);
        float2 v0; v0.x = x0r[PERM(r)]; v0.y = x0i[PERM(r)]; buf0[a] = v0;
        float2 v1; v1.x = x1r[PERM(r)]; v1.y = x1i[PERM(r)]; buf1[a] = v1;
    }
    __syncthreads();

    // ---- Phase E: inv L=4096, pruned (k<2048), fused float4 stores (4 cols)
#pragma unroll
    for (int r = 0; r < 16; ++r) {
        int a = P(t + 256 * r);
        float2 v0 = buf0[a]; x0r[r] = v0.x; x0i[r] = v0.y;
        float2 v1 = buf1[a]; x1r[r] = v1.x; x1i[r] = v1.y;
    }
#pragma unroll
    for (int r = 1; r < 16; ++r) {
        float2 w = tw4096[r * 256 + t];
        cmulc(x0r[r], x0i[r], w.x, w.y);
        cmulc(x1r[r], x1i[r], w.x, w.y);
    }
    dft16_layer1<1>(x0r, x0i); dft16_layer1<1>(x1r, x1i);
    dft16_twiddle<1>(x0r, x0i); dft16_twiddle<1>(x1r, x1i);
    float* ob = out + ((size_t)b * N_) * E_ + quad * 4;
#pragma unroll
    for (int k1 = 0; k1 < 4; ++k1) {
        // pruned final dft4 (outputs r=k1 and r=k1+4 only), both streams
        float a0r = x0r[4 * k1],     a0i = x0i[4 * k1];
        float a1r = x0r[4 * k1 + 1], a1i = x0i[4 * k1 + 1];
        float a2r = x0r[4 * k1 + 2], a2i = x0i[4 * k1 + 2];
        float a3r = x0r[4 * k1 + 3], a3i = x0i[4 * k1 + 3];
        float t0r = a0r + a2r, t0i = a0i + a2i;
        float t1r = a0r - a2r, t1i = a0i - a2i;
        float t2r = a1r + a3r, t2i = a1i + a3i;
        float t3r = a1r - a3r, t3i = a1i - a3i;
        float s0v0r = t0r + t2r, s0v0i = t0i + t2i;
        float s0v1r = t1r - t3i, s0v1i = t1i + t3r;
        a0r = x1r[4 * k1];     a0i = x1i[4 * k1];
        a1r = x1r[4 * k1 + 1]; a1i = x1i[4 * k1 + 1];
        a2r = x1r[4 * k1 + 2]; a2i = x1i[4 * k1 + 2];
        a3r = x1r[4 * k1 + 3]; a3i = x1i[4 * k1 + 3];
        t0r = a0r + a2r; t0i = a0i + a2i;
        t1r = a0r - a2r; t1i = a0i - a2i;
        t2r = a1r + a3r; t2i = a1i + a3i;
        t3r = a1r - a3r; t3i = a1i - a3i;
        float s1v0r = t0r + t2r, s1v0i = t0i + t2i;
        float s1v1r = t1r - t3i, s1v1i = t1i + t3r;
        float4 w0; w0.x = s0v0r; w0.y = s0v0i; w0.z = s1v0r; w0.w = s1v0i;
        float4 w1; w1.x = s0v1r; w1.y = s0v1i; w1.z = s1v1r; w1.w = s1v1i;
        *(float4*)(ob + (size_t)(t + 256 * k1) * E_)       = w0;   // k=t+256k1
        *(float4*)(ob + (size_t)(t + 256 * (k1 + 4)) * E_) = w1;   // k=t+256(k1+4)
    }
}

// ---------------- fallback (ws too small): direct fp32 dot -------------------
__global__ __launch_bounds__(256) void naive_toep(const float* __restrict__ x,
                                                  const float* __restrict__ pos,
                                                  const float* __restrict__ zero,
                                                  const float* __restrict__ neg,
                                                  float* __restrict__ out) {
    int bid = blockIdx.x;
    int e   = (bid & 3) * 256 + threadIdx.x;
    int k   = (bid >> 2) & (N_ - 1);
    int b   = bid >> 13;
    float zv = zero[0];
    float acc = 0.f;
    const float* xb = x + (size_t)b * N_ * E_ + e;
    for (int jj = 0; jj < N_; ++jj) {
        float c = (jj < k) ? pos[k - jj - 1] : (jj == k) ? zv : neg[N_ - 1 - jj + k];
        acc += c * xb[(size_t)jj * E_];
    }
    out[((size_t)(b * N_ + k)) * E_ + e] = acc;
}

extern "C" void kernel_launch(void* const* d_in, const int* in_sizes, int n_in,
                              void* d_out, int out_size, void* d_ws, size_t ws_size,
                              hipStream_t stream) {
    const float* x    = (const float*)d_in[0];
    const float* pos  = (const float*)d_in[1];
    const float* zero = (const float*)d_in[2];
    const float* neg  = (const float*)d_in[3];
    float* out = (float*)d_out;

    const size_t needX = (size_t)B_ * 512 * N_ * sizeof(uint32_t);   // 32 MiB
    const size_t need  = needX + (2 * (size_t)NF + 256) * sizeof(float2);
    if (ws_size >= need) {
        uint32_t* xP   = (uint32_t*)d_ws;
        float2* tw4096 = (float2*)((char*)d_ws + needX);
        float2* tw256  = tw4096 + NF;
        float2* V2     = tw256 + 256;
        prep<<<18 + 4096, 256, 0, stream>>>(x, pos, zero, neg, xP, tw4096, tw256, V2);
        fft_conv<<<2048, 256, 0, stream>>>(xP, tw4096, tw256, V2, out);
    } else {
        naive_toep<<<65536, 256, 0, stream>>>(x, pos, zero, neg, out);
    }
}

// Round 10
// 175.542 us; speedup vs baseline: 1.8660x; 1.0085x over previous
//
#include <hip/hip_runtime.h>
#include <stdint.h>

// Toeplitz matvec = circular conv via batched 4096-pt radix-16 FFT (3 stages).
// v10: ILP=2 (two FFTs/block, R9) + bf16-PACKED LDS: each complex stored as
// u32 (bf16 re | bf16 im<<16) -> 16KB/FFT, 32KB/block total. Restores
// 4-5 blocks/CU (R9's 64KB allowed only 2 -> per-dispatch regression) while
// keeping the ILP=2 dep-stall hiding R9 proved out, and halves LDS traffic
// (b32 reads @5.8cyc vs b64 @12cyc). 4 intermediate bf16 roundings add
// ~0.3-0.6 absmax (threshold 3.58, current 1.0 - safe).
// ws: xP u32[8][512][2048] (32MiB) + tw4096 f2[4096] + tw256 f2[256] + V2 f2[4096].

#define B_ 8
#define N_ 2048
#define NF 4096
#define E_ 1024

// Bank swizzle, b32 banks (bank = idx mod 32). All phase patterns
// (t+256r / 256g+16r+j / 16t+r) verified exactly 2 lanes/bank = free (m136).
__device__ __forceinline__ int P(int n) {
    return n ^ ((n >> 4) & 15) ^ ((n >> 8) & 15) ^ (((n >> 9) & 1) << 4);
}
#define PERM(r) ((((r) & 3) << 2) | ((r) >> 2))   // DFT16 reg<->index transpose

__device__ __forceinline__ unsigned short f32_to_bf16_rne(float f) {
    union { float f; unsigned int u; } cv; cv.f = f;
    unsigned int u = cv.u;
    u += 0x7fffu + ((u >> 16) & 1u);
    return (unsigned short)(u >> 16);
}
__device__ __forceinline__ float bf16_to_f32(unsigned short u) {
    union { unsigned int u; float f; } cv; cv.u = ((unsigned int)u) << 16; return cv.f;
}
// pack complex (re,im) -> u32: low16 = bf16(re), high16 = bf16(im). RNE both.
__device__ __forceinline__ uint32_t cpack(float re, float im) {
    union { float f; uint32_t u; } a, b; a.f = re; b.f = im;
    uint32_t ua = a.u + (0x7fffu + ((a.u >> 16) & 1u));
    uint32_t ub = b.u + (0x7fffu + ((b.u >> 16) & 1u));
    return __builtin_amdgcn_perm(ub, ua, 0x07060302u);  // {ub.b3,ub.b2,ua.b3,ua.b2}
}
__device__ __forceinline__ void cunpack(uint32_t u, float& re, float& im) {
    union { uint32_t u; float f; } a, b;
    a.u = u << 16; b.u = u & 0xffff0000u;
    re = a.f; im = b.f;
}
__device__ __forceinline__ void cmul(float& ar, float& ai, float br, float bi) {
    float t = ar * br - ai * bi; ai = ar * bi + ai * br; ar = t;
}
__device__ __forceinline__ void cmulc(float& ar, float& ai, float br, float bi) {
    float t = ar * br + ai * bi; ai = ai * br - ar * bi; ar = t;   // a *= conj(b)
}

__device__ __forceinline__ void dft4(float& x0r, float& x0i, float& x1r, float& x1i,
                                     float& x2r, float& x2i, float& x3r, float& x3i,
                                     float sg) {
    float t0r = x0r + x2r, t0i = x0i + x2i;
    float t1r = x0r - x2r, t1i = x0i - x2i;
    float t2r = x1r + x3r, t2i = x1i + x3i;
    float t3r = x1r - x3r, t3i = x1i - x3i;
    x0r = t0r + t2r; x0i = t0i + t2i;
    x2r = t0r - t2r; x2i = t0i - t2i;
    x1r = t1r - sg * t3i; x1i = t1i + sg * t3r;
    x3r = t1r + sg * t3i; x3i = t1i - sg * t3r;
}

template<int SG>
__device__ __forceinline__ void dft16_layer1(float* xr, float* xi) {
    const float sg = (float)SG;
#pragma unroll
    for (int n0 = 0; n0 < 4; ++n0)
        dft4(xr[n0], xi[n0], xr[n0 + 4], xi[n0 + 4],
             xr[n0 + 8], xi[n0 + 8], xr[n0 + 12], xi[n0 + 12], sg);
}
// upper 8 inputs (slots 8..15) known zero
template<int SG>
__device__ __forceinline__ void dft16_layer1_pad(float* xr, float* xi) {
    const float sg = (float)SG;
#pragma unroll
    for (int n0 = 0; n0 < 4; ++n0) {
        float ar = xr[n0], ai = xi[n0], br = xr[n0 + 4], bi = xi[n0 + 4];
        xr[n0]      = ar + br;       xi[n0]      = ai + bi;
        xr[n0 + 4]  = ar - sg * bi;  xi[n0 + 4]  = ai + sg * br;
        xr[n0 + 8]  = ar - br;       xi[n0 + 8]  = ai - bi;
        xr[n0 + 12] = ar + sg * bi;  xi[n0 + 12] = ai - sg * br;
    }
}
template<int SG>
__device__ __forceinline__ void dft16_twiddle(float* xr, float* xi) {
    const float sg = (float)SG;
    const float C1 = 0.923879532511286756f;
    const float S1 = 0.382683432365089772f;
    const float H  = 0.707106781186547524f;
    cmul(xr[5],  xi[5],  C1,  sg * S1);
    cmul(xr[9],  xi[9],  H,   sg * H);
    cmul(xr[13], xi[13], S1,  sg * C1);
    cmul(xr[6],  xi[6],  H,   sg * H);
    cmul(xr[10], xi[10], 0.f, sg);
    cmul(xr[14], xi[14], -H,  sg * H);
    cmul(xr[7],  xi[7],  S1,  sg * C1);
    cmul(xr[11], xi[11], -H,  sg * H);
    cmul(xr[15], xi[15], -C1, -sg * S1);
}
template<int SG>
__device__ __forceinline__ void dft16_layer2(float* xr, float* xi) {
    const float sg = (float)SG;
#pragma unroll
    for (int k1 = 0; k1 < 4; ++k1)
        dft4(xr[4 * k1], xi[4 * k1], xr[4 * k1 + 1], xi[4 * k1 + 1],
             xr[4 * k1 + 2], xi[4 * k1 + 2], xr[4 * k1 + 3], xi[4 * k1 + 3], sg);
}
template<int SG>
__device__ __forceinline__ void dft16(float* xr, float* xi) {
    dft16_layer1<SG>(xr, xi);
    dft16_twiddle<SG>(xr, xi);
    dft16_layer2<SG>(xr, xi);
}

// forward radix-16 stage with inline sincos twiddles (V build only, 1 block)
template<int L>
__device__ __forceinline__ void fwd_stage_sincos(float2* buf, int t) {
    constexpr int Lq = L / 16;
    int g = t / Lq;
    int j = t - g * Lq;
    int base = g * L + j;
    const float TPI = -6.28318530717958647692f;
    float xr[16], xi[16];
#pragma unroll
    for (int r = 0; r < 16; ++r) {
        float2 v = buf[P(base + r * Lq)];
        xr[r] = v.x; xi[r] = v.y;
    }
    dft16<-1>(xr, xi);
    { float2 v; v.x = xr[0]; v.y = xi[0]; buf[P(base)] = v; }
#pragma unroll
    for (int r = 1; r < 16; ++r) {
        float s, c;
        __sincosf(TPI * (float)(j * r) * (1.f / (float)L), &s, &c);
        float yr = xr[PERM(r)], yi = xi[PERM(r)];
        cmul(yr, yi, c, s);
        float2 v; v.x = yr; v.y = yi;
        buf[P(base + r * Lq)] = v;
    }
}

// ---------------- prep: tables + V + pair-interleaved transpose --------------
// (unchanged from R9 — measured faster than prior layouts)
__global__ __launch_bounds__(256) void prep(const float* __restrict__ x,
                                            const float* __restrict__ pos,
                                            const float* __restrict__ zero,
                                            const float* __restrict__ neg,
                                            uint32_t* __restrict__ xP,
                                            float2* __restrict__ tw4096,
                                            float2* __restrict__ tw256,
                                            float2* __restrict__ V2) {
    __shared__ __align__(16) char smraw[32768];
    const float TPI = -6.28318530717958647692f;
    int blk = blockIdx.x, t = threadIdx.x;
    if (blk < 16) {
        float s, c;
        __sincosf(TPI * (float)(blk * t) * (1.f / 4096.f), &s, &c);
        float2 v; v.x = c; v.y = s;
        tw4096[blk * 256 + t] = v;
    } else if (blk == 16) {
        int r = t >> 4, j = t & 15;
        float s, c;
        __sincosf(TPI * (float)(r * j) * (1.f / 256.f), &s, &c);
        float2 v; v.x = c; v.y = s;
        tw256[t] = v;
    } else if (blk == 17) {
        float2* buf = (float2*)smraw;
#pragma unroll
        for (int it = 0; it < 16; ++it) {
            int n = t + 256 * it;
            float v;
            if (n == 0) v = zero[0];
            else if (n < N_) v = pos[n - 1];
            else if (n == N_) v = zero[0];
            else v = neg[n - (N_ + 1)];
            float2 cc; cc.x = v; cc.y = 0.f;
            buf[P(n)] = cc;
        }
        __syncthreads();
        fwd_stage_sincos<4096>(buf, t); __syncthreads();
        fwd_stage_sincos<256>(buf, t);  __syncthreads();
        fwd_stage_sincos<16>(buf, t);   __syncthreads();
        const float s = 1.f / (float)NF;
#pragma unroll
        for (int it = 0; it < 16; ++it) {
            int n = t + 256 * it;
            float2 c = buf[P(n)];
            c.x *= s; c.y *= s;
            V2[n] = c;
        }
    } else {
        float (*tile)[66] = (float (*)[66])smraw;    // 64*66*4 = 16.9 KB
        int tid = blk - 18;
        int e0 = (tid & 15) * 64;                    // e-tile base
        int j0 = ((tid >> 4) & 31) * 64;             // n-tile base
        int b  = tid >> 9;
        int e4 = t & 15, jr = t >> 4;
#pragma unroll
        for (int it = 0; it < 4; ++it) {
            int j = jr + it * 16;
            const float4 v = *(const float4*)(x + ((size_t)(b * N_ + j0 + j) * E_) + e0 + e4 * 4);
            tile[e4 * 4 + 0][j] = v.x;
            tile[e4 * 4 + 1][j] = v.y;
            tile[e4 * 4 + 2][j] = v.z;
            tile[e4 * 4 + 3][j] = v.w;
        }
        __syncthreads();
        int jj = t & 63, ur = t >> 6;                // ur 0..3
#pragma unroll
        for (int it = 0; it < 8; ++it) {
            int u = ur + it * 4;                     // pair-local 0..31
            union { unsigned short s[2]; uint32_t w; } pk;
            pk.s[0] = f32_to_bf16_rne(tile[2 * u][jj]);
            pk.s[1] = f32_to_bf16_rne(tile[2 * u + 1][jj]);
            xP[((size_t)(b * 512 + (e0 >> 1) + u)) * N_ + j0 + jj] = pk.w;
        }
    }
}

// ---------------- main: FFT-conv, TWO pairs/block, bf16-packed LDS -----------
__global__ __launch_bounds__(256) void fft_conv(const uint32_t* __restrict__ xP,
                                                const float2* __restrict__ tw4096,
                                                const float2* __restrict__ tw256,
                                                const float2* __restrict__ V2,
                                                float* __restrict__ out) {
    __shared__ uint32_t buf0[NF];           // 16 KB
    __shared__ uint32_t buf1[NF];           // 16 KB -> 32 KB total
    int t = threadIdx.x;
    int bid = blockIdx.x;                   // 2048
    int xcd = bid & 7;
    int q = bid >> 3;                       // 0..255
    int b = q >> 5;                         // 0..7
    int quad = xcd * 32 + (q & 31);         // 0..255 -> e0 = quad*4
    const uint32_t* g0 = xP + ((size_t)(b * 512 + quad * 2)) * N_;
    const uint32_t* g1 = g0 + N_;

    float x0r[16], x0i[16], x1r[16], x1i[16];

    // ---- Phase A: fwd L=4096 from global; slots 8..15 zero
#pragma unroll
    for (int r = 0; r < 8; ++r) {
        int n = t + 256 * r;
        cunpack(g0[n], x0r[r], x0i[r]);
        cunpack(g1[n], x1r[r], x1i[r]);
    }
#pragma unroll
    for (int r = 8; r < 16; ++r) { x0r[r] = 0.f; x0i[r] = 0.f; x1r[r] = 0.f; x1i[r] = 0.f; }
    dft16_layer1_pad<-1>(x0r, x0i); dft16_layer1_pad<-1>(x1r, x1i);
    dft16_twiddle<-1>(x0r, x0i);    dft16_twiddle<-1>(x1r, x1i);
    dft16_layer2<-1>(x0r, x0i);     dft16_layer2<-1>(x1r, x1i);
    buf0[P(t)] = cpack(x0r[0], x0i[0]);
    buf1[P(t)] = cpack(x1r[0], x1i[0]);
#pragma unroll
    for (int r = 1; r < 16; ++r) {
        float2 w = tw4096[r * 256 + t];                 // shared twiddle
        int a = P(t + 256 * r);
        float y0r = x0r[PERM(r)], y0i = x0i[PERM(r)];
        cmul(y0r, y0i, w.x, w.y);
        buf0[a] = cpack(y0r, y0i);
        float y1r = x1r[PERM(r)], y1i = x1i[PERM(r)];
        cmul(y1r, y1i, w.x, w.y);
        buf1[a] = cpack(y1r, y1i);
    }
    __syncthreads();

    // ---- Phase B: fwd L=256
    int g = t >> 4, j = t & 15;
    int base = g * 256 + j;
#pragma unroll
    for (int r = 0; r < 16; ++r) {
        int a = P(base + 16 * r);
        cunpack(buf0[a], x0r[r], x0i[r]);
        cunpack(buf1[a], x1r[r], x1i[r]);
    }
    dft16<-1>(x0r, x0i); dft16<-1>(x1r, x1i);
    buf0[P(base)] = cpack(x0r[0], x0i[0]);
    buf1[P(base)] = cpack(x1r[0], x1i[0]);
#pragma unroll
    for (int r = 1; r < 16; ++r) {
        float2 w = tw256[r * 16 + j];
        int a = P(base + 16 * r);
        float y0r = x0r[PERM(r)], y0i = x0i[PERM(r)];
        cmul(y0r, y0i, w.x, w.y);
        buf0[a] = cpack(y0r, y0i);
        float y1r = x1r[PERM(r)], y1i = x1i[PERM(r)];
        cmul(y1r, y1i, w.x, w.y);
        buf1[a] = cpack(y1r, y1i);
    }
    __syncthreads();

    // ---- Phase C: fwd L=16 + pointwise*V (shared) + inv L=16, in place
    {
        int mb = 16 * t;
#pragma unroll
        for (int r = 0; r < 16; ++r) {
            int a = P(mb + r);
            cunpack(buf0[a], x0r[r], x0i[r]);
            cunpack(buf1[a], x1r[r], x1i[r]);
        }
        dft16<-1>(x0r, x0i); dft16<-1>(x1r, x1i);
        // y[r] = x[PERM(r)]*V[r]; PERM involution -> pair swap, V shared
#pragma unroll
        for (int r = 0; r < 16; ++r) {
            int p = PERM(r);
            if (p < r) continue;
            if (p == r) {
                float2 vv = V2[mb + r];
                float ar = x0r[r], ai = x0i[r];
                x0r[r] = ar * vv.x - ai * vv.y; x0i[r] = ar * vv.y + ai * vv.x;
                ar = x1r[r]; ai = x1i[r];
                x1r[r] = ar * vv.x - ai * vv.y; x1i[r] = ar * vv.y + ai * vv.x;
            } else {
                float2 va = V2[mb + r], vb = V2[mb + p];
                float ar = x0r[r], ai = x0i[r], br = x0r[p], bi = x0i[p];
                x0r[r] = br * va.x - bi * va.y; x0i[r] = br * va.y + bi * va.x;
                x0r[p] = ar * vb.x - ai * vb.y; x0i[p] = ar * vb.y + ai * vb.x;
                ar = x1r[r]; ai = x1i[r]; br = x1r[p]; bi = x1i[p];
                x1r[r] = br * va.x - bi * va.y; x1i[r] = br * va.y + bi * va.x;
                x1r[p] = ar * vb.x - ai * vb.y; x1i[p] = ar * vb.y + ai * vb.x;
            }
        }
        dft16<1>(x0r, x0i); dft16<1>(x1r, x1i);
#pragma unroll
        for (int r = 0; r < 16; ++r) {
            int a = P(mb + r);
            buf0[a] = cpack(x0r[PERM(r)], x0i[PERM(r)]);
            buf1[a] = cpack(x1r[PERM(r)], x1i[PERM(r)]);
        }
    }
    __syncthreads();

    // ---- Phase D: inv L=256
#pragma unroll
    for (int r = 0; r < 16; ++r) {
        int a = P(base + 16 * r);
        cunpack(buf0[a], x0r[r], x0i[r]);
        cunpack(buf1[a], x1r[r], x1i[r]);
    }
#pragma unroll
    for (int r = 1; r < 16; ++r) {
        float2 w = tw256[r * 16 + j];
        cmulc(x0r[r], x0i[r], w.x, w.y);
        cmulc(x1r[r], x1i[r], w.x, w.y);
    }
    dft16<1>(x0r, x0i); dft16<1>(x1r, x1i);
#pragma unroll
    for (int r = 0; r < 16; ++r) {
        int a = P(base + 16 * r);
        buf0[a] = cpack(x0r[PERM(r)], x0i[PERM(r)]);
        buf1[a] = cpack(x1r[PERM(r)], x1i[PERM(r)]);
    }
    __syncthreads();

    // ---- Phase E: inv L=4096, pruned (k<2048), fused float4 stores (4 cols)
#pragma unroll
    for (int r = 0; r < 16; ++r) {
        int a = P(t + 256 * r);
        cunpack(buf0[a], x0r[r], x0i[r]);
        cunpack(buf1[a], x1r[r], x1i[r]);
    }
#pragma unroll
    for (int r = 1; r < 16; ++r) {
        float2 w = tw4096[r * 256 + t];
        cmulc(x0r[r], x0i[r], w.x, w.y);
        cmulc(x1r[r], x1i[r], w.x, w.y);
    }
    dft16_layer1<1>(x0r, x0i); dft16_layer1<1>(x1r, x1i);
    dft16_twiddle<1>(x0r, x0i); dft16_twiddle<1>(x1r, x1i);
    float* ob = out + ((size_t)b * N_) * E_ + quad * 4;
#pragma unroll
    for (int k1 = 0; k1 < 4; ++k1) {
        // pruned final dft4 (outputs r=k1 and r=k1+4 only), both streams
        float a0r = x0r[4 * k1],     a0i = x0i[4 * k1];
        float a1r = x0r[4 * k1 + 1], a1i = x0i[4 * k1 + 1];
        float a2r = x0r[4 * k1 + 2], a2i = x0i[4 * k1 + 2];
        float a3r = x0r[4 * k1 + 3], a3i = x0i[4 * k1 + 3];
        float t0r = a0r + a2r, t0i = a0i + a2i;
        float t1r = a0r - a2r, t1i = a0i - a2i;
        float t2r = a1r + a3r, t2i = a1i + a3i;
        float t3r = a1r - a3r, t3i = a1i - a3i;
        float s0v0r = t0r + t2r, s0v0i = t0i + t2i;
        float s0v1r = t1r - t3i, s0v1i = t1i + t3r;
        a0r = x1r[4 * k1];     a0i = x1i[4 * k1];
        a1r = x1r[4 * k1 + 1]; a1i = x1i[4 * k1 + 1];
        a2r = x1r[4 * k1 + 2]; a2i = x1i[4 * k1 + 2];
        a3r = x1r[4 * k1 + 3]; a3i = x1i[4 * k1 + 3];
        t0r = a0r + a2r; t0i = a0i + a2i;
        t1r = a0r - a2r; t1i = a0i - a2i;
        t2r = a1r + a3r; t2i = a1i + a3i;
        t3r = a1r - a3r; t3i = a1i - a3i;
        float s1v0r = t0r + t2r, s1v0i = t0i + t2i;
        float s1v1r = t1r - t3i, s1v1i = t1i + t3r;
        float4 w0; w0.x = s0v0r; w0.y = s0v0i; w0.z = s1v0r; w0.w = s1v0i;
        float4 w1; w1.x = s0v1r; w1.y = s0v1i; w1.z = s1v1r; w1.w = s1v1i;
        *(float4*)(ob + (size_t)(t + 256 * k1) * E_)       = w0;   // k=t+256k1
        *(float4*)(ob + (size_t)(t + 256 * (k1 + 4)) * E_) = w1;   // k=t+256(k1+4)
    }
}

// ---------------- fallback (ws too small): direct fp32 dot -------------------
__global__ __launch_bounds__(256) void naive_toep(const float* __restrict__ x,
                                                  const float* __restrict__ pos,
                                                  const float* __restrict__ zero,
                                                  const float* __restrict__ neg,
                                                  float* __restrict__ out) {
    int bid = blockIdx.x;
    int e   = (bid & 3) * 256 + threadIdx.x;
    int k   = (bid >> 2) & (N_ - 1);
    int b   = bid >> 13;
    float zv = zero[0];
    float acc = 0.f;
    const float* xb = x + (size_t)b * N_ * E_ + e;
    for (int jj = 0; jj < N_; ++jj) {
        float c = (jj < k) ? pos[k - jj - 1] : (jj == k) ? zv : neg[N_ - 1 - jj + k];
        acc += c * xb[(size_t)jj * E_];
    }
    out[((size_t)(b * N_ + k)) * E_ + e] = acc;
}

extern "C" void kernel_launch(void* const* d_in, const int* in_sizes, int n_in,
                              void* d_out, int out_size, void* d_ws, size_t ws_size,
                              hipStream_t stream) {
    const float* x    = (const float*)d_in[0];
    const float* pos  = (const float*)d_in[1];
    const float* zero = (const float*)d_in[2];
    const float* neg  = (const float*)d_in[3];
    float* out = (float*)d_out;

    const size_t needX = (size_t)B_ * 512 * N_ * sizeof(uint32_t);   // 32 MiB
    const size_t need  = needX + (2 * (size_t)NF + 256) * sizeof(float2);
    if (ws_size >= need) {
        uint32_t* xP   = (uint32_t*)d_ws;
        float2* tw4096 = (float2*)((char*)d_ws + needX);
        float2* tw256  = tw4096 + NF;
        float2* V2     = tw256 + 256;
        prep<<<18 + 4096, 256, 0, stream>>>(x, pos, zero, neg, xP, tw4096, tw256, V2);
        fft_conv<<<2048, 256, 0, stream>>>(xP, tw4096, tw256, V2, out);
    } else {
        naive_toep<<<65536, 256, 0, stream>>>(x, pos, zero, neg, out);
    }
}